// Round 7
// baseline (151.933 us; speedup 1.0000x reference)
//
#include <hip/hip_runtime.h>
#include <stdint.h>

#define NH   16
#define EMB  1024
#define HD   64
#define BSZ  2
#define SEQ  2048
#define NROW (BSZ * SEQ)          // 4096

typedef __attribute__((ext_vector_type(8))) short bf16x8;   // 8 bf16 = 4 VGPRs
typedef __attribute__((ext_vector_type(4))) float f32x4;    // MFMA C/D

__device__ __forceinline__ uint16_t f2bf(float f) {
    union { float f; uint32_t i; } v; v.f = f;
    uint32_t r = v.i + 0x7FFFu + ((v.i >> 16) & 1u);  // RNE
    return (uint16_t)(r >> 16);
}
__device__ __forceinline__ uint32_t pack2(float a, float b) {
    return (uint32_t)f2bf(a) | ((uint32_t)f2bf(b) << 16);
}
// single-instruction packed f32->bf16 (lo=a, hi=b), RNE
__device__ __forceinline__ uint32_t cvtpk(float a, float b) {
    uint32_t r;
    asm("v_cvt_pk_bf16_f32 %0, %1, %2" : "=v"(r) : "v"(a), "v"(b));
    return r;
}

// async global->LDS, 16 B per lane, wave-uniform LDS base
__device__ __forceinline__ void gl2lds16(const uint16_t* g, uint16_t* l) {
    __builtin_amdgcn_global_load_lds(
        static_cast<const uint32_t*>(static_cast<const void*>(g)),
        static_cast<uint32_t*>(static_cast<void*>(l)), 16, 0, 0);
}

// =====================================================================
// Prep (W only; X conversion fused into the GEMM): 288 blocks
// transpose W fp32 [k][n] -> bf16 Wt[n][k].
// =====================================================================
__global__ __launch_bounds__(256) void prep_w(
    const float* __restrict__ Wq, const float* __restrict__ Wk,
    const float* __restrict__ Wv, uint16_t* __restrict__ Wqt,
    uint16_t* __restrict__ Wkt, uint16_t* __restrict__ Wvt)
{
    __shared__ uint16_t T[64][72];
    const int tid = threadIdx.x;
    const int id = blockIdx.x;
    const float* W; uint16_t* Wt; int k0, n0, ldw;
    if (id < 256)      { W = Wq; Wt = Wqt; k0 = (id >> 4) * 64; n0 = (id & 15) * 64; ldw = EMB; }
    else if (id < 272) { W = Wk; Wt = Wkt; k0 = (id - 256) * 64; n0 = 0; ldw = HD; }
    else               { W = Wv; Wt = Wvt; k0 = (id - 272) * 64; n0 = 0; ldw = HD; }

    const int r = tid >> 2, c4 = (tid & 3) * 16;
#pragma unroll
    for (int i = 0; i < 4; ++i) {
        float4 wv = *(const float4*)&W[(size_t)(k0 + r) * ldw + n0 + c4 + 4 * i];
        T[r][c4 + 4 * i + 0] = f2bf(wv.x); T[r][c4 + 4 * i + 1] = f2bf(wv.y);
        T[r][c4 + 4 * i + 2] = f2bf(wv.z); T[r][c4 + 4 * i + 3] = f2bf(wv.w);
    }
    __syncthreads();
    const int n = tid >> 2, kk = (tid & 3) * 16;
    uint32_t o[8];
#pragma unroll
    for (int i = 0; i < 8; ++i)
        o[i] = (uint32_t)T[kk + 2 * i][n] | ((uint32_t)T[kk + 2 * i + 1][n] << 16);
    uint16_t* dst = &Wt[(size_t)(n0 + n) * EMB + k0 + kk];
    *(uint4*)dst       = make_uint4(o[0], o[1], o[2], o[3]);
    *(uint4*)(dst + 8) = make_uint4(o[4], o[5], o[6], o[7]);
}

// =====================================================================
// Kernel 1: MFMA projection GEMM v6.  64M x 128N tiles, BK=64,
// grid (9, 64) = 576 blocks.  A staged directly from fp32 X
// (reg-stage -> cvt_pk -> ds_write_b128); B via gl2lds16 DMA.
// (unchanged this round)
// =====================================================================
__global__ __launch_bounds__(256) void qkv_gemm_mfma6(
    const float* __restrict__ X, const uint16_t* __restrict__ Wqt,
    const uint16_t* __restrict__ Wkt, const uint16_t* __restrict__ Wvt,
    float* __restrict__ Qout, uint16_t* __restrict__ Kbf,
    uint16_t* __restrict__ Vtbf)
{
    const int tid  = threadIdx.x;
    const int w    = tid >> 6, lane = tid & 63;
    const int l    = lane & 15, quad = lane >> 4;
    const int wm   = w & 1, wn = w >> 1;      // wave: 32m x 64n quadrant
    const int nt   = blockIdx.x;
    const int m0   = blockIdx.y * 64;

    __shared__ uint16_t As[2][64 * 64];    // 8 KB per buffer
    __shared__ uint16_t Bs[2][128 * 64];   // 16 KB per buffer

    // ---- A staging: per-lane fp32 source for swizzled LDS granules ----
    const float* gAx[2]; uint32_t ldsA[2];
#pragma unroll
    for (int i = 0; i < 2; ++i) {
        int G = (w * 2 + i) * 64 + lane;
        int r = G >> 3, cg = (G & 7) ^ (r & 7);
        gAx[i] = &X[(size_t)(m0 + r) * EMB + cg * 8];
        ldsA[i] = (uint32_t)G * 8;                 // elems
    }
    // ---- B staging: gl2lds16 from pre-transposed bf16 W ----
    const uint16_t* gB[4]; uint32_t ldsB[4];
#pragma unroll
    for (int i = 0; i < 4; ++i) {
        int G = (w * 4 + i) * 64 + lane;
        int r = G >> 3, cg = (G & 7) ^ (r & 7);
        const uint16_t* bs;
        if (nt < 8)      bs = &Wqt[(size_t)(nt * 128 + r) * EMB + cg * 8];
        else if (r < 64) bs = &Wkt[(size_t)r * EMB + cg * 8];
        else             bs = &Wvt[(size_t)(r - 64) * EMB + cg * 8];
        gB[i] = bs;
        ldsB[i] = (w * 4 + i) * 512;
    }

    // ---- fragment read offsets (elems), loop-invariant ----
    uint32_t offA[2][2], offB[4][2];
#pragma unroll
    for (int i = 0; i < 2; ++i)
#pragma unroll
        for (int kh = 0; kh < 2; ++kh) {
            int row = 32 * wm + 16 * i + l;
            offA[i][kh] = row * 64 + (((kh * 4 + quad) ^ (row & 7)) * 8);
        }
#pragma unroll
    for (int j = 0; j < 4; ++j)
#pragma unroll
        for (int kh = 0; kh < 2; ++kh) {
            int row = 64 * wn + 16 * j + l;
            offB[j][kh] = row * 64 + (((kh * 4 + quad) ^ (row & 7)) * 8);
        }

    f32x4 acc[2][4] = {};

    // ---- prologue: stage ks=0 ----
    float4 a0[2], a1[2];
#pragma unroll
    for (int i = 0; i < 2; ++i) {
        a0[i] = *(const float4*)gAx[i];
        a1[i] = *(const float4*)(gAx[i] + 4);
        gAx[i] += 64;
    }
#pragma unroll
    for (int i = 0; i < 4; ++i) { gl2lds16(gB[i], &Bs[0][ldsB[i]]); gB[i] += 64; }
#pragma unroll
    for (int i = 0; i < 2; ++i)
        *(uint4*)&As[0][ldsA[i]] =
            make_uint4(cvtpk(a0[i].x, a0[i].y), cvtpk(a0[i].z, a0[i].w),
                       cvtpk(a1[i].x, a1[i].y), cvtpk(a1[i].z, a1[i].w));
    __syncthreads();

    for (int ks = 0; ks < 16; ++ks) {
        const int cur = ks & 1, nxt = cur ^ 1;
        if (ks < 15) {
#pragma unroll
            for (int i = 0; i < 2; ++i) {
                a0[i] = *(const float4*)gAx[i];
                a1[i] = *(const float4*)(gAx[i] + 4);
                gAx[i] += 64;
            }
#pragma unroll
            for (int i = 0; i < 4; ++i) { gl2lds16(gB[i], &Bs[nxt][ldsB[i]]); gB[i] += 64; }
        }
#pragma unroll
        for (int kh = 0; kh < 2; ++kh) {
            bf16x8 af[2], bfr[4];
#pragma unroll
            for (int i = 0; i < 2; ++i) af[i] = *(const bf16x8*)&As[cur][offA[i][kh]];
#pragma unroll
            for (int j = 0; j < 4; ++j) bfr[j] = *(const bf16x8*)&Bs[cur][offB[j][kh]];
#pragma unroll
            for (int i = 0; i < 2; ++i)
#pragma unroll
                for (int j = 0; j < 4; ++j)
                    acc[i][j] = __builtin_amdgcn_mfma_f32_16x16x32_bf16(
                        af[i], bfr[j], acc[i][j], 0, 0, 0);
        }
        if (ks < 15) {
#pragma unroll
            for (int i = 0; i < 2; ++i)
                *(uint4*)&As[nxt][ldsA[i]] =
                    make_uint4(cvtpk(a0[i].x, a0[i].y), cvtpk(a0[i].z, a0[i].w),
                               cvtpk(a1[i].x, a1[i].y), cvtpk(a1[i].z, a1[i].w));
        }
        __syncthreads();
    }

    // ---- epilogue.  C layout: col = l (n), row = quad*4 + r (m). ----
    if (nt < 8) {             // Q -> fp32 d_out
#pragma unroll
        for (int i = 0; i < 2; ++i)
#pragma unroll
            for (int j = 0; j < 4; ++j)
#pragma unroll
                for (int r = 0; r < 4; ++r)
                    Qout[(size_t)(m0 + 32 * wm + 16 * i + 4 * quad + r) * EMB
                         + nt * 128 + 64 * wn + 16 * j + l] = acc[i][j][r];
    } else if (wn == 0) {     // K -> bf16 [t][d]
#pragma unroll
        for (int i = 0; i < 2; ++i)
#pragma unroll
            for (int j = 0; j < 4; ++j)
#pragma unroll
                for (int r = 0; r < 4; ++r)
                    Kbf[(size_t)(m0 + 32 * wm + 16 * i + 4 * quad + r) * HD
                        + 16 * j + l] = f2bf(acc[i][j][r]);
    } else {                  // V -> bf16 transposed [d][t]
#pragma unroll
        for (int i = 0; i < 2; ++i)
#pragma unroll
            for (int j = 0; j < 4; ++j)
#pragma unroll
                for (int r = 0; r < 4; ++r)
                    Vtbf[(size_t)(16 * j + l) * NROW
                         + m0 + 32 * wm + 16 * i + 4 * quad + r] = f2bf(acc[i][j][r]);
    }
}

// =====================================================================
// Kernel 2: causal MQA flash attention.
// R18: UN-PAIRED blocks -- one 64-row q-tile per block, grid
// (32, NH, BSZ) = 1024 blocks = 4/CU (was 512 = 2/CU, grid-limited).
// 4 waves/SIMD doubles latency hiding; long blocks (qt=31) launch
// first for causal balance.  Ps eliminated: Q staged through Ks[0]
// scratch before the first K DMA -> LDS = 32.0 KB/block (5/CU cap).
// Carries over (HW-verified): pi-K rows, XOR granule swizzle, DMA
// staging, in-register P, MFMA row-sum denominator, peeled diagonal.
// =====================================================================
__global__ __launch_bounds__(256, 4) void mqa_attn(
    const uint16_t* __restrict__ Kbf, const uint16_t* __restrict__ Vtbf,
    float* __restrict__ Out)
{
    const int tid  = threadIdx.x;
    const int w    = tid >> 6;            // 0..3
    const int lane = tid & 63;
    const int l    = lane & 15;
    const int quad = lane >> 4;
    const int h  = blockIdx.y, b = blockIdx.z;
    const int qt = 31 - blockIdx.x;       // longest first
    const int q0 = qt * 64;

    __shared__ __align__(16) uint16_t Ks[2][4096];  // K dbuf (pi rows, swz) 16 KB
    __shared__ __align__(16) uint16_t Vs[2][4096];  // V^T dbuf (swz)       16 KB

    const float C = 0.125f * 1.4426950408889634f;   // scale * log2e
    const int sr = tid >> 2, sc = (tid & 3) * 16;

    // ---- DMA staging sources: slot = w*2+i2 (8 slots x 64 lanes = 512
    //      granules = one 8 KB tile).  LDS granule (r,g) holds:
    //      K row pi(r), col-granule g^(r&7);  V^T row r, col g^(r&7).
    const uint16_t* kSrc[2]; const uint16_t* vSrc[2]; uint32_t dstE[2];
#pragma unroll
    for (int i2 = 0; i2 < 2; ++i2) {
        int G = (w * 2 + i2) * 64 + lane;
        int r = G >> 3, g = G & 7;
        int pr = (r & 32) + ((r >> 2) & 3) * 8 + ((r & 16) >> 2) + (r & 3);
        int cg = g ^ (r & 7);
        kSrc[i2] = &Kbf[(size_t)(b * SEQ + pr) * HD + cg * 8];
        vSrc[i2] = &Vtbf[(size_t)r * NROW + b * SEQ + cg * 8];
        dstE[i2] = (uint32_t)(w * 2 + i2) * 512;   // elems
    }

    // ---- stage Q (pre-scaled, swizzled) into Ks[0] scratch ----
    {
        const float* src = &Out[(size_t)(b * SEQ + q0 + sr) * EMB + h * HD + sc];
        float4 f0 = *(const float4*)(src + 0);
        float4 f1 = *(const float4*)(src + 4);
        float4 f2 = *(const float4*)(src + 8);
        float4 f3 = *(const float4*)(src + 12);
        const int g0 = sc >> 3;          // granule of first 8 elems
        *(uint4*)&Ks[0][sr * 64 + ((g0 ^ (sr & 7)) * 8)] =
            make_uint4(pack2(f0.x * C, f0.y * C), pack2(f0.z * C, f0.w * C),
                       pack2(f1.x * C, f1.y * C), pack2(f1.z * C, f1.w * C));
        *(uint4*)&Ks[0][sr * 64 + (((g0 + 1) ^ (sr & 7)) * 8)] =
            make_uint4(pack2(f2.x * C, f2.y * C), pack2(f2.z * C, f2.w * C),
                       pack2(f3.x * C, f3.y * C), pack2(f3.z * C, f3.w * C));
    }
    __syncthreads();

    // ---- Q B-fragments from scratch (swizzled read) ----
    bf16x8 qf[2];
    {
        const int row = 16 * w + l;
        qf[0] = *(const bf16x8*)&Ks[0][row * 64 + (((0 + quad) ^ (row & 7)) * 8)];
        qf[1] = *(const bf16x8*)&Ks[0][row * 64 + (((4 + quad) ^ (row & 7)) * 8)];
    }
    __syncthreads();   // qf reads done before DMA overwrites Ks[0]

    // ---- DMA tile 0 (K,V) ----
#pragma unroll
    for (int i2 = 0; i2 < 2; ++i2) {
        gl2lds16(kSrc[i2], &Ks[0][dstE[i2]]);
        gl2lds16(vSrc[i2], &Vs[0][dstE[i2]]);
        kSrc[i2] += 64 * HD;   // next k-tile = +64 rows
        vSrc[i2] += 64;        // next k-tile = +64 cols
    }
    __syncthreads();   // drain DMA

    // ---- loop-invariant LDS read offsets (same for Ks and Vs) ----
    uint32_t off[4][2];
#pragma unroll
    for (int ts = 0; ts < 4; ++ts)
#pragma unroll
        for (int kh = 0; kh < 2; ++kh)
            off[ts][kh] = (16 * ts + l) * 64 + (((4 * kh + quad) ^ (l & 7)) * 8);

    bf16x8 ones;
#pragma unroll
    for (int j = 0; j < 8; ++j) ones[j] = (short)0x3F80;   // bf16 1.0

    f32x4 accO[4] = {};
    f32x4 accSum = {};
    const int qi_l = 16 * w + l;

    // ---- one k-tile step; M compile-time at each call site ----
    auto body = [&](int kb, bool M) __attribute__((always_inline)) {
        const int cur = kb & 1, nxt = cur ^ 1;

        // K / V fragments from LDS (swizzled)
        bf16x8 ka[4][2], vb[4][2];
#pragma unroll
        for (int ts = 0; ts < 4; ++ts) {
            ka[ts][0] = *(const bf16x8*)&Ks[cur][off[ts][0]];
            ka[ts][1] = *(const bf16x8*)&Ks[cur][off[ts][1]];
            vb[ts][0] = *(const bf16x8*)&Vs[cur][off[ts][0]];
            vb[ts][1] = *(const bf16x8*)&Vs[cur][off[ts][1]];
        }

        // DMA-stage tile kb+1 into idle buffers
        if (kb < qt) {
#pragma unroll
            for (int i2 = 0; i2 < 2; ++i2) {
                gl2lds16(kSrc[i2], &Ks[nxt][dstE[i2]]);
                gl2lds16(vSrc[i2], &Vs[nxt][dstE[i2]]);
                kSrc[i2] += 64 * HD;
                vSrc[i2] += 64;
            }
        }

        // QK^T
        f32x4 accS[4] = {};
#pragma unroll
        for (int ts = 0; ts < 4; ++ts) {
            accS[ts] = __builtin_amdgcn_mfma_f32_16x16x32_bf16(ka[ts][0], qf[0], accS[ts], 0, 0, 0);
            accS[ts] = __builtin_amdgcn_mfma_f32_16x16x32_bf16(ka[ts][1], qf[1], accS[ts], 0, 0, 0);
        }

        // exp2 / mask / in-register pa build
        float pv[16];
#pragma unroll
        for (int ts = 0; ts < 4; ++ts)
#pragma unroll
            for (int r = 0; r < 4; ++r)
                pv[4 * ts + r] = exp2f(accS[ts][r]);
        if (M) {
            // k-position of pv[4ts+r] is 32(ts>=2) + 8quad + 4(ts&1) + r
#pragma unroll
            for (int ts = 0; ts < 4; ++ts)
#pragma unroll
                for (int r = 0; r < 4; ++r)
                    if ((((ts & 2) << 4) + ((ts & 1) << 2) + 8 * quad + r) > qi_l)
                        pv[4 * ts + r] = 0.f;
        }
        union { uint32_t u[4]; bf16x8 v; } A0, A1;
#pragma unroll
        for (int j = 0; j < 4; ++j) A0.u[j] = cvtpk(pv[2 * j],     pv[2 * j + 1]);
#pragma unroll
        for (int j = 0; j < 4; ++j) A1.u[j] = cvtpk(pv[8 + 2 * j], pv[9 + 2 * j]);

        // PV + MFMA row-sum denominator
#pragma unroll
        for (int tn = 0; tn < 4; ++tn) {
            accO[tn] = __builtin_amdgcn_mfma_f32_16x16x32_bf16(A0.v, vb[tn][0], accO[tn], 0, 0, 0);
            accO[tn] = __builtin_amdgcn_mfma_f32_16x16x32_bf16(A1.v, vb[tn][1], accO[tn], 0, 0, 0);
        }
        accSum = __builtin_amdgcn_mfma_f32_16x16x32_bf16(A0.v, ones, accSum, 0, 0, 0);
        accSum = __builtin_amdgcn_mfma_f32_16x16x32_bf16(A1.v, ones, accSum, 0, 0, 0);

        if (kb < qt) __syncthreads();   // [cur] reads done; DMA for nxt drained
    };

    for (int kb = 0; kb < qt; ++kb) body(kb, false);
    body(qt, true);                    // diagonal tile

    // ---- epilogue: denominator lane-aligned with accO rows ----
#pragma unroll
    for (int r = 0; r < 4; ++r) {
        float invr = 1.0f / accSum[r];
        const int row = q0 + 16 * w + 4 * quad + r;
#pragma unroll
        for (int tn = 0; tn < 4; ++tn)
            Out[(size_t)(b * SEQ + row) * EMB + h * HD + 16 * tn + l] =
                accO[tn][r] * invr;
    }
}

// =====================================================================
// Fallback (proven): fp32 vector GEMM (writes same layouts).
// =====================================================================
__global__ __launch_bounds__(256) void qkv_gemm_vec(
    const float* __restrict__ X,  const float* __restrict__ Wq,
    const float* __restrict__ Wk, const float* __restrict__ Wv,
    float* __restrict__ Qout, uint16_t* __restrict__ Kbf,
    uint16_t* __restrict__ Vtbf)
{
    const int tid = threadIdx.x;
    const int tx = tid & 15, ty = tid >> 4;
    const int bx = blockIdx.x;
    const int m0 = blockIdx.y * 64;

    const float* W; int ldw, n0;
    if (bx < 16)       { W = Wq; ldw = EMB; n0 = bx * 64; }
    else if (bx == 16) { W = Wk; ldw = HD;  n0 = 0; }
    else               { W = Wv; ldw = HD;  n0 = 0; }

    __shared__ float sA[64][17];
    __shared__ float sB[16][64];

    float acc[4][4] = {};
    const int arow = tid >> 2, acol = (tid & 3) * 4;
    const int brow = tid >> 4, bcol = (tid & 15) * 4;

    for (int k0 = 0; k0 < EMB; k0 += 16) {
        float4 fa = *(const float4*)&X[(size_t)(m0 + arow) * EMB + k0 + acol];
        float4 fb = *(const float4*)&W[(size_t)(k0 + brow) * ldw + n0 + bcol];
        sA[arow][acol + 0] = fa.x; sA[arow][acol + 1] = fa.y;
        sA[arow][acol + 2] = fa.z; sA[arow][acol + 3] = fa.w;
        sB[brow][bcol + 0] = fb.x; sB[brow][bcol + 1] = fb.y;
        sB[brow][bcol + 2] = fb.z; sB[brow][bcol + 3] = fb.w;
        __syncthreads();
#pragma unroll
        for (int kk = 0; kk < 16; ++kk) {
            float a0 = sA[4 * ty + 0][kk];
            float a1 = sA[4 * ty + 1][kk];
            float a2 = sA[4 * ty + 2][kk];
            float a3 = sA[4 * ty + 3][kk];
            float4 bq = *(const float4*)&sB[kk][4 * tx];
            acc[0][0] += a0 * bq.x; acc[0][1] += a0 * bq.y; acc[0][2] += a0 * bq.z; acc[0][3] += a0 * bq.w;
            acc[1][0] += a1 * bq.x; acc[1][1] += a1 * bq.y; acc[1][2] += a1 * bq.z; acc[1][3] += a1 * bq.w;
            acc[2][0] += a2 * bq.x; acc[2][1] += a2 * bq.y; acc[2][2] += a2 * bq.z; acc[2][3] += a2 * bq.w;
            acc[3][0] += a3 * bq.x; acc[3][1] += a3 * bq.y; acc[3][2] += a3 * bq.z; acc[3][3] += a3 * bq.w;
        }
        __syncthreads();
    }

    if (bx < 16) {
#pragma unroll
        for (int i = 0; i < 4; ++i)
            *(float4*)&Qout[(size_t)(m0 + 4 * ty + i) * EMB + n0 + 4 * tx] =
                make_float4(acc[i][0], acc[i][1], acc[i][2], acc[i][3]);
    } else if (bx == 16) {
#pragma unroll
        for (int i = 0; i < 4; ++i) {
            ushort4 u; u.x = f2bf(acc[i][0]); u.y = f2bf(acc[i][1]);
            u.z = f2bf(acc[i][2]); u.w = f2bf(acc[i][3]);
            *(ushort4*)&Kbf[(size_t)(m0 + 4 * ty + i) * HD + 4 * tx] = u;
        }
    } else {
#pragma unroll
        for (int j = 0; j < 4; ++j) {
            ushort4 u; u.x = f2bf(acc[0][j]); u.y = f2bf(acc[1][j]);
            u.z = f2bf(acc[2][j]); u.w = f2bf(acc[3][j]);
            *(ushort4*)&Vtbf[(size_t)(4 * tx + j) * NROW + m0 + 4 * ty] = u;
        }
    }
}

extern "C" void kernel_launch(void* const* d_in, const int* in_sizes, int n_in,
                              void* d_out, int out_size, void* d_ws, size_t ws_size,
                              hipStream_t stream) {
    const float* X  = (const float*)d_in[0];
    const float* Wq = (const float*)d_in[1];
    const float* Wk = (const float*)d_in[2];
    const float* Wv = (const float*)d_in[3];
    float* OutP = (float*)d_out;

    // ws layout (3.25 MiB):
    //   Wqt  [1024][1024] bf16   2 MiB  @ 0
    //   Wkt  [64][1024]   bf16 128 KiB  @ 2 MiB
    //   Wvt  [64][1024]   bf16 128 KiB  @ 2 MiB + 128 KiB
    //   Kbf  [4096][64]   bf16 512 KiB  @ 2 MiB + 256 KiB
    //   Vtbf [64][4096]   bf16 512 KiB  @ 2 MiB + 768 KiB
    char* ws = (char*)d_ws;
    const size_t MB = 1024 * 1024;
    const size_t KB = 1024;
    uint16_t* Wqt  = (uint16_t*)(ws);
    uint16_t* Wkt  = (uint16_t*)(ws + 2 * MB);
    uint16_t* Wvt  = (uint16_t*)(ws + 2 * MB + 128 * KB);
    uint16_t* Kbf  = (uint16_t*)(ws + 2 * MB + 256 * KB);
    uint16_t* Vtbf = (uint16_t*)(ws + 2 * MB + 768 * KB);

    if (ws_size >= 4 * MB) {
        prep_w<<<288, 256, 0, stream>>>(Wq, Wk, Wv, Wqt, Wkt, Wvt);
        qkv_gemm_mfma6<<<dim3(9, 64), 256, 0, stream>>>(X, Wqt, Wkt, Wvt,
                                                        OutP, Kbf, Vtbf);
        mqa_attn<<<dim3(32, NH, BSZ), 256, 0, stream>>>(Kbf, Vtbf, OutP);
    } else {
        uint16_t* KbfS  = (uint16_t*)d_ws;
        uint16_t* VtbfS = KbfS + (size_t)NROW * HD;
        qkv_gemm_vec<<<dim3(18, 64), 256, 0, stream>>>(X, Wq, Wk, Wv, OutP, KbfS, VtbfS);
        mqa_attn<<<dim3(32, NH, BSZ), 256, 0, stream>>>(KbfS, VtbfS, OutP);
    }
}

// Round 8
// 132.189 us; speedup vs baseline: 1.1494x; 1.1494x over previous
//
#include <hip/hip_runtime.h>
#include <stdint.h>

#define NH   16
#define EMB  1024
#define HD   64
#define BSZ  2
#define SEQ  2048
#define NROW (BSZ * SEQ)          // 4096

typedef __attribute__((ext_vector_type(8))) short bf16x8;   // 8 bf16 = 4 VGPRs
typedef __attribute__((ext_vector_type(4))) float f32x4;    // MFMA C/D

__device__ __forceinline__ uint16_t f2bf(float f) {
    union { float f; uint32_t i; } v; v.f = f;
    uint32_t r = v.i + 0x7FFFu + ((v.i >> 16) & 1u);  // RNE
    return (uint16_t)(r >> 16);
}
__device__ __forceinline__ uint32_t pack2(float a, float b) {
    return (uint32_t)f2bf(a) | ((uint32_t)f2bf(b) << 16);
}
// single-instruction packed f32->bf16 (lo=a, hi=b), RNE
__device__ __forceinline__ uint32_t cvtpk(float a, float b) {
    uint32_t r;
    asm("v_cvt_pk_bf16_f32 %0, %1, %2" : "=v"(r) : "v"(a), "v"(b));
    return r;
}

// async global->LDS, 16 B per lane, wave-uniform LDS base
__device__ __forceinline__ void gl2lds16(const uint16_t* g, uint16_t* l) {
    __builtin_amdgcn_global_load_lds(
        static_cast<const uint32_t*>(static_cast<const void*>(g)),
        static_cast<uint32_t*>(static_cast<void*>(l)), 16, 0, 0);
}

// =====================================================================
// Prep (fused): blocks 0..2047 convert X fp32->bf16;
// blocks 2048..2335 transpose W fp32 [k][n] -> bf16 Wt[n][k].
// (R5-proven: separate Xbf pass; bf16 X re-read 9x in GEMM beats fp32.)
// =====================================================================
__global__ __launch_bounds__(256) void prep(
    const float* __restrict__ X, uint16_t* __restrict__ Xbf,
    const float* __restrict__ Wq, const float* __restrict__ Wk,
    const float* __restrict__ Wv, uint16_t* __restrict__ Wqt,
    uint16_t* __restrict__ Wkt, uint16_t* __restrict__ Wvt)
{
    __shared__ uint16_t T[64][72];
    const int tid = threadIdx.x;
    if (blockIdx.x < 2048) {
        size_t idx = ((size_t)blockIdx.x * 256 + tid) * 8;
        float4 a = *(const float4*)&X[idx];
        float4 b = *(const float4*)&X[idx + 4];
        *(uint4*)&Xbf[idx] = make_uint4(pack2(a.x, a.y), pack2(a.z, a.w),
                                        pack2(b.x, b.y), pack2(b.z, b.w));
        return;
    }
    const int id = blockIdx.x - 2048;
    const float* W; uint16_t* Wt; int k0, n0, ldw;
    if (id < 256)      { W = Wq; Wt = Wqt; k0 = (id >> 4) * 64; n0 = (id & 15) * 64; ldw = EMB; }
    else if (id < 272) { W = Wk; Wt = Wkt; k0 = (id - 256) * 64; n0 = 0; ldw = HD; }
    else               { W = Wv; Wt = Wvt; k0 = (id - 272) * 64; n0 = 0; ldw = HD; }

    const int r = tid >> 2, c4 = (tid & 3) * 16;
#pragma unroll
    for (int i = 0; i < 4; ++i) {
        float4 wv = *(const float4*)&W[(size_t)(k0 + r) * ldw + n0 + c4 + 4 * i];
        T[r][c4 + 4 * i + 0] = f2bf(wv.x); T[r][c4 + 4 * i + 1] = f2bf(wv.y);
        T[r][c4 + 4 * i + 2] = f2bf(wv.z); T[r][c4 + 4 * i + 3] = f2bf(wv.w);
    }
    __syncthreads();
    const int n = tid >> 2, kk = (tid & 3) * 16;
    uint32_t o[8];
#pragma unroll
    for (int i = 0; i < 8; ++i)
        o[i] = (uint32_t)T[kk + 2 * i][n] | ((uint32_t)T[kk + 2 * i + 1][n] << 16);
    uint16_t* dst = &Wt[(size_t)(n0 + n) * EMB + k0 + kk];
    *(uint4*)dst       = make_uint4(o[0], o[1], o[2], o[3]);
    *(uint4*)(dst + 8) = make_uint4(o[4], o[5], o[6], o[7]);
}

// =====================================================================
// Kernel 1: MFMA projection GEMM v5 (R5-proven).  64M x 128N, BK=64,
// grid (9, 64) = 576 blocks, XOR granule swizzle both sides.
// =====================================================================
__global__ __launch_bounds__(256) void qkv_gemm_mfma5(
    const uint16_t* __restrict__ Xbf, const uint16_t* __restrict__ Wqt,
    const uint16_t* __restrict__ Wkt, const uint16_t* __restrict__ Wvt,
    float* __restrict__ Qout, uint16_t* __restrict__ Kbf,
    uint16_t* __restrict__ Vtbf)
{
    const int tid  = threadIdx.x;
    const int w    = tid >> 6, lane = tid & 63;
    const int l    = lane & 15, quad = lane >> 4;
    const int wm   = w & 1, wn = w >> 1;      // wave: 32m x 64n quadrant
    const int nt   = blockIdx.x;
    const int m0   = blockIdx.y * 64;

    __shared__ uint16_t As[2][64 * 64];    // 8 KB per buffer
    __shared__ uint16_t Bs[2][128 * 64];   // 16 KB per buffer

    const uint16_t* gA[2]; uint32_t ldsA[2];
    const uint16_t* gB[4]; uint32_t ldsB[4];
#pragma unroll
    for (int i = 0; i < 2; ++i) {
        int G = (w * 2 + i) * 64 + lane;
        int r = G >> 3, cg = (G & 7) ^ (r & 7);
        gA[i] = &Xbf[(size_t)(m0 + r) * EMB + cg * 8];
        ldsA[i] = (w * 2 + i) * 512;              // elems, wave-uniform
    }
#pragma unroll
    for (int i = 0; i < 4; ++i) {
        int G = (w * 4 + i) * 64 + lane;
        int r = G >> 3, cg = (G & 7) ^ (r & 7);
        const uint16_t* bs;
        if (nt < 8)      bs = &Wqt[(size_t)(nt * 128 + r) * EMB + cg * 8];
        else if (r < 64) bs = &Wkt[(size_t)r * EMB + cg * 8];
        else             bs = &Wvt[(size_t)(r - 64) * EMB + cg * 8];
        gB[i] = bs;
        ldsB[i] = (w * 4 + i) * 512;
    }

    uint32_t offA[2][2], offB[4][2];
#pragma unroll
    for (int i = 0; i < 2; ++i)
#pragma unroll
        for (int kh = 0; kh < 2; ++kh) {
            int row = 32 * wm + 16 * i + l;
            offA[i][kh] = row * 64 + (((kh * 4 + quad) ^ (row & 7)) * 8);
        }
#pragma unroll
    for (int j = 0; j < 4; ++j)
#pragma unroll
        for (int kh = 0; kh < 2; ++kh) {
            int row = 64 * wn + 16 * j + l;
            offB[j][kh] = row * 64 + (((kh * 4 + quad) ^ (row & 7)) * 8);
        }

    f32x4 acc[2][4] = {};

#pragma unroll
    for (int i = 0; i < 2; ++i) { gl2lds16(gA[i], &As[0][ldsA[i]]); gA[i] += 64; }
#pragma unroll
    for (int i = 0; i < 4; ++i) { gl2lds16(gB[i], &Bs[0][ldsB[i]]); gB[i] += 64; }
    __syncthreads();

    for (int ks = 0; ks < 16; ++ks) {
        const int cur = ks & 1, nxt = cur ^ 1;
        if (ks < 15) {
#pragma unroll
            for (int i = 0; i < 2; ++i) { gl2lds16(gA[i], &As[nxt][ldsA[i]]); gA[i] += 64; }
#pragma unroll
            for (int i = 0; i < 4; ++i) { gl2lds16(gB[i], &Bs[nxt][ldsB[i]]); gB[i] += 64; }
        }
#pragma unroll
        for (int kh = 0; kh < 2; ++kh) {
            bf16x8 af[2], bfr[4];
#pragma unroll
            for (int i = 0; i < 2; ++i) af[i] = *(const bf16x8*)&As[cur][offA[i][kh]];
#pragma unroll
            for (int j = 0; j < 4; ++j) bfr[j] = *(const bf16x8*)&Bs[cur][offB[j][kh]];
#pragma unroll
            for (int i = 0; i < 2; ++i)
#pragma unroll
                for (int j = 0; j < 4; ++j)
                    acc[i][j] = __builtin_amdgcn_mfma_f32_16x16x32_bf16(
                        af[i], bfr[j], acc[i][j], 0, 0, 0);
        }
        __syncthreads();
    }

    if (nt < 8) {             // Q -> fp32 d_out
#pragma unroll
        for (int i = 0; i < 2; ++i)
#pragma unroll
            for (int j = 0; j < 4; ++j)
#pragma unroll
                for (int r = 0; r < 4; ++r)
                    Qout[(size_t)(m0 + 32 * wm + 16 * i + 4 * quad + r) * EMB
                         + nt * 128 + 64 * wn + 16 * j + l] = acc[i][j][r];
    } else if (wn == 0) {     // K -> bf16 [t][d]
#pragma unroll
        for (int i = 0; i < 2; ++i)
#pragma unroll
            for (int j = 0; j < 4; ++j)
#pragma unroll
                for (int r = 0; r < 4; ++r)
                    Kbf[(size_t)(m0 + 32 * wm + 16 * i + 4 * quad + r) * HD
                        + 16 * j + l] = f2bf(acc[i][j][r]);
    } else {                  // V -> bf16 transposed [d][t]
#pragma unroll
        for (int i = 0; i < 2; ++i)
#pragma unroll
            for (int j = 0; j < 4; ++j)
#pragma unroll
                for (int r = 0; r < 4; ++r)
                    Vtbf[(size_t)(16 * j + l) * NROW
                         + m0 + 32 * wm + 16 * i + 4 * quad + r] = f2bf(acc[i][j][r]);
    }
}

// =====================================================================
// Kernel 2: causal MQA flash attention, COMPLEMENTARY-PAIR blocks
// (R6-proven: exactly 33 bodies/block = perfect static balance under
// full residency; unpaired variant regressed 42->55 via per-CU load
// variance).  DMA staging with pre-swizzled sources (pi-K rows + XOR
// granule swizzle, conflicts=0), in-register P, MFMA row-sum denom.
// Grid (16, NH, BSZ) = 512 blocks.
// =====================================================================
__global__ __launch_bounds__(256) void mqa_attn(
    const uint16_t* __restrict__ Kbf, const uint16_t* __restrict__ Vtbf,
    float* __restrict__ Out)
{
    const int tid  = threadIdx.x;
    const int w    = tid >> 6;
    const int lane = tid & 63;
    const int l    = lane & 15;
    const int quad = lane >> 4;
    const int i  = blockIdx.x;            // 0..15 (i=0 longest)
    const int h  = blockIdx.y, b = blockIdx.z;
    const int qt0 = 31 - i, qt1 = i;      // big, small q-tile
    const int q00 = qt0 * 64, q01 = qt1 * 64;

    __shared__ __align__(16) uint16_t Ks[2][4096];  // K dbuf (pi rows, swz)
    __shared__ __align__(16) uint16_t Vs[2][4096];  // V^T dbuf (swz)
    __shared__ __align__(16) uint16_t Ps[2][64][72];   // Q staging

    const float C = 0.125f * 1.4426950408889634f;      // scale * log2e
    const int sr = tid >> 2, sc = (tid & 3) * 16;

    // ---- DMA staging sources: slot = w*2+i2; LDS granule (r,g) holds
    //      K row pi(r) col-granule g^(r&7);  V^T row r col g^(r&7).
    const uint16_t* kSrc[2]; const uint16_t* vSrc[2]; uint32_t dstE[2];
#pragma unroll
    for (int i2 = 0; i2 < 2; ++i2) {
        int G = (w * 2 + i2) * 64 + lane;
        int r = G >> 3, g = G & 7;
        int pr = (r & 32) + ((r >> 2) & 3) * 8 + ((r & 16) >> 2) + (r & 3);
        int cg = g ^ (r & 7);
        kSrc[i2] = &Kbf[(size_t)(b * SEQ + pr) * HD + cg * 8];
        vSrc[i2] = &Vtbf[(size_t)r * NROW + b * SEQ + cg * 8];
        dstE[i2] = (uint32_t)(w * 2 + i2) * 512;   // elems
    }

    // ---- stage tile 0 via DMA ----
#pragma unroll
    for (int i2 = 0; i2 < 2; ++i2) {
        gl2lds16(kSrc[i2], &Ks[0][dstE[i2]]);
        gl2lds16(vSrc[i2], &Vs[0][dstE[i2]]);
        kSrc[i2] += 64 * HD;   // next k-tile = +64 rows
        vSrc[i2] += 64;        // next k-tile = +64 cols
    }

    // ---- stage Q for both q-tiles (pre-scaled) into Ps ----
#pragma unroll
    for (int t = 0; t < 2; ++t) {
        const int q0t = t ? q01 : q00;
        const float* src = &Out[(size_t)(b * SEQ + q0t + sr) * EMB + h * HD + sc];
        float4 f0 = *(const float4*)(src + 0);
        float4 f1 = *(const float4*)(src + 4);
        float4 f2 = *(const float4*)(src + 8);
        float4 f3 = *(const float4*)(src + 12);
        *(uint4*)&Ps[t][sr][sc] =
            make_uint4(pack2(f0.x * C, f0.y * C), pack2(f0.z * C, f0.w * C),
                       pack2(f1.x * C, f1.y * C), pack2(f1.z * C, f1.w * C));
        *(uint4*)&Ps[t][sr][sc + 8] =
            make_uint4(pack2(f2.x * C, f2.y * C), pack2(f2.z * C, f2.w * C),
                       pack2(f3.x * C, f3.y * C), pack2(f3.z * C, f3.w * C));
    }
    __syncthreads();   // drains DMA (vmcnt) + Q writes

    // ---- Q B-fragments for both q-tiles ----
    bf16x8 qf[2][2];
#pragma unroll
    for (int t = 0; t < 2; ++t) {
        qf[t][0] = *(const bf16x8*)&Ps[t][16 * w + l][quad * 8];
        qf[t][1] = *(const bf16x8*)&Ps[t][16 * w + l][32 + quad * 8];
    }

    // ---- loop-invariant LDS read offsets (same for Ks and Vs) ----
    uint32_t off[4][2];
#pragma unroll
    for (int ts = 0; ts < 4; ++ts)
#pragma unroll
        for (int kh = 0; kh < 2; ++kh)
            off[ts][kh] = (16 * ts + l) * 64 + (((4 * kh + quad) ^ (l & 7)) * 8);

    bf16x8 ones;
#pragma unroll
    for (int j = 0; j < 8; ++j) ones[j] = (short)0x3F80;   // bf16 1.0

    f32x4 accO[2][4] = {};
    f32x4 accSum[2] = {};
    const int qi_l = 16 * w + l;

    // ---- one k-tile step; DO1/M0/M1 compile-time at each call site ----
    auto body = [&](int kb, bool DO1, bool M0, bool M1) __attribute__((always_inline)) {
        const int cur = kb & 1, nxt = cur ^ 1;

        // K / V fragments from LDS (swizzled)
        bf16x8 ka[4][2], vb[4][2];
#pragma unroll
        for (int ts = 0; ts < 4; ++ts) {
            ka[ts][0] = *(const bf16x8*)&Ks[cur][off[ts][0]];
            ka[ts][1] = *(const bf16x8*)&Ks[cur][off[ts][1]];
            vb[ts][0] = *(const bf16x8*)&Vs[cur][off[ts][0]];
            vb[ts][1] = *(const bf16x8*)&Vs[cur][off[ts][1]];
        }

        // DMA-stage tile kb+1 into idle buffers
        if (kb < qt0) {
#pragma unroll
            for (int i2 = 0; i2 < 2; ++i2) {
                gl2lds16(kSrc[i2], &Ks[nxt][dstE[i2]]);
                gl2lds16(vSrc[i2], &Vs[nxt][dstE[i2]]);
                kSrc[i2] += 64 * HD;
                vSrc[i2] += 64;
            }
        }

        // QK^T for both tiles
        f32x4 accS0[4] = {}, accS1[4] = {};
#pragma unroll
        for (int ts = 0; ts < 4; ++ts) {
            accS0[ts] = __builtin_amdgcn_mfma_f32_16x16x32_bf16(ka[ts][0], qf[0][0], accS0[ts], 0, 0, 0);
            accS0[ts] = __builtin_amdgcn_mfma_f32_16x16x32_bf16(ka[ts][1], qf[0][1], accS0[ts], 0, 0, 0);
        }
        if (DO1) {
#pragma unroll
            for (int ts = 0; ts < 4; ++ts) {
                accS1[ts] = __builtin_amdgcn_mfma_f32_16x16x32_bf16(ka[ts][0], qf[1][0], accS1[ts], 0, 0, 0);
                accS1[ts] = __builtin_amdgcn_mfma_f32_16x16x32_bf16(ka[ts][1], qf[1][1], accS1[ts], 0, 0, 0);
            }
        }

        // tile 0: exp2 / mask / in-register pa build / PV
        {
            float pv[16];
#pragma unroll
            for (int ts = 0; ts < 4; ++ts)
#pragma unroll
                for (int r = 0; r < 4; ++r)
                    pv[4 * ts + r] = exp2f(accS0[ts][r]);
            if (M0) {
                // k-position of pv[4ts+r] is 32(ts>=2) + 8quad + 4(ts&1) + r
#pragma unroll
                for (int ts = 0; ts < 4; ++ts)
#pragma unroll
                    for (int r = 0; r < 4; ++r)
                        if ((((ts & 2) << 4) + ((ts & 1) << 2) + 8 * quad + r) > qi_l)
                            pv[4 * ts + r] = 0.f;
            }
            union { uint32_t u[4]; bf16x8 v; } A0, A1;
#pragma unroll
            for (int j = 0; j < 4; ++j) A0.u[j] = cvtpk(pv[2 * j],     pv[2 * j + 1]);
#pragma unroll
            for (int j = 0; j < 4; ++j) A1.u[j] = cvtpk(pv[8 + 2 * j], pv[9 + 2 * j]);
#pragma unroll
            for (int tn = 0; tn < 4; ++tn) {
                accO[0][tn] = __builtin_amdgcn_mfma_f32_16x16x32_bf16(A0.v, vb[tn][0], accO[0][tn], 0, 0, 0);
                accO[0][tn] = __builtin_amdgcn_mfma_f32_16x16x32_bf16(A1.v, vb[tn][1], accO[0][tn], 0, 0, 0);
            }
            accSum[0] = __builtin_amdgcn_mfma_f32_16x16x32_bf16(A0.v, ones, accSum[0], 0, 0, 0);
            accSum[0] = __builtin_amdgcn_mfma_f32_16x16x32_bf16(A1.v, ones, accSum[0], 0, 0, 0);
        }
        // tile 1
        if (DO1) {
            float pv[16];
#pragma unroll
            for (int ts = 0; ts < 4; ++ts)
#pragma unroll
                for (int r = 0; r < 4; ++r)
                    pv[4 * ts + r] = exp2f(accS1[ts][r]);
            if (M1) {
#pragma unroll
                for (int ts = 0; ts < 4; ++ts)
#pragma unroll
                    for (int r = 0; r < 4; ++r)
                        if ((((ts & 2) << 4) + ((ts & 1) << 2) + 8 * quad + r) > qi_l)
                            pv[4 * ts + r] = 0.f;
            }
            union { uint32_t u[4]; bf16x8 v; } A0, A1;
#pragma unroll
            for (int j = 0; j < 4; ++j) A0.u[j] = cvtpk(pv[2 * j],     pv[2 * j + 1]);
#pragma unroll
            for (int j = 0; j < 4; ++j) A1.u[j] = cvtpk(pv[8 + 2 * j], pv[9 + 2 * j]);
#pragma unroll
            for (int tn = 0; tn < 4; ++tn) {
                accO[1][tn] = __builtin_amdgcn_mfma_f32_16x16x32_bf16(A0.v, vb[tn][0], accO[1][tn], 0, 0, 0);
                accO[1][tn] = __builtin_amdgcn_mfma_f32_16x16x32_bf16(A1.v, vb[tn][1], accO[1][tn], 0, 0, 0);
            }
            accSum[1] = __builtin_amdgcn_mfma_f32_16x16x32_bf16(A0.v, ones, accSum[1], 0, 0, 0);
            accSum[1] = __builtin_amdgcn_mfma_f32_16x16x32_bf16(A1.v, ones, accSum[1], 0, 0, 0);
        }

        if (kb < qt0) __syncthreads();   // [cur] reads done; DMA for nxt drained
    };

    // ---- segmented k-loop: branch-free bodies, peeled diagonals ----
    for (int kb = 0; kb < qt1; ++kb) body(kb, true,  false, false);
    body(qt1, true,  false, true);                 // tile-1 diagonal
    for (int kb = qt1 + 1; kb < qt0; ++kb) body(kb, false, false, false);
    body(qt0, false, true,  false);                // tile-0 diagonal

    // ---- epilogue: denominator lane-aligned with accO rows ----
#pragma unroll
    for (int t = 0; t < 2; ++t) {
        const int q0t = t ? q01 : q00;
#pragma unroll
        for (int r = 0; r < 4; ++r) {
            float invr = 1.0f / accSum[t][r];
            const int row = q0t + 16 * w + 4 * quad + r;
#pragma unroll
            for (int tn = 0; tn < 4; ++tn)
                Out[(size_t)(b * SEQ + row) * EMB + h * HD + 16 * tn + l] =
                    accO[t][tn][r] * invr;
        }
    }
}

// =====================================================================
// Fallback (proven): fp32 vector GEMM (writes same layouts).
// =====================================================================
__global__ __launch_bounds__(256) void qkv_gemm_vec(
    const float* __restrict__ X,  const float* __restrict__ Wq,
    const float* __restrict__ Wk, const float* __restrict__ Wv,
    float* __restrict__ Qout, uint16_t* __restrict__ Kbf,
    uint16_t* __restrict__ Vtbf)
{
    const int tid = threadIdx.x;
    const int tx = tid & 15, ty = tid >> 4;
    const int bx = blockIdx.x;
    const int m0 = blockIdx.y * 64;

    const float* W; int ldw, n0;
    if (bx < 16)       { W = Wq; ldw = EMB; n0 = bx * 64; }
    else if (bx == 16) { W = Wk; ldw = HD;  n0 = 0; }
    else               { W = Wv; ldw = HD;  n0 = 0; }

    __shared__ float sA[64][17];
    __shared__ float sB[16][64];

    float acc[4][4] = {};
    const int arow = tid >> 2, acol = (tid & 3) * 4;
    const int brow = tid >> 4, bcol = (tid & 15) * 4;

    for (int k0 = 0; k0 < EMB; k0 += 16) {
        float4 fa = *(const float4*)&X[(size_t)(m0 + arow) * EMB + k0 + acol];
        float4 fb = *(const float4*)&W[(size_t)(k0 + brow) * ldw + n0 + bcol];
        sA[arow][acol + 0] = fa.x; sA[arow][acol + 1] = fa.y;
        sA[arow][acol + 2] = fa.z; sA[arow][acol + 3] = fa.w;
        sB[brow][bcol + 0] = fb.x; sB[brow][bcol + 1] = fb.y;
        sB[brow][bcol + 2] = fb.z; sB[brow][bcol + 3] = fb.w;
        __syncthreads();
#pragma unroll
        for (int kk = 0; kk < 16; ++kk) {
            float a0 = sA[4 * ty + 0][kk];
            float a1 = sA[4 * ty + 1][kk];
            float a2 = sA[4 * ty + 2][kk];
            float a3 = sA[4 * ty + 3][kk];
            float4 bq = *(const float4*)&sB[kk][4 * tx];
            acc[0][0] += a0 * bq.x; acc[0][1] += a0 * bq.y; acc[0][2] += a0 * bq.z; acc[0][3] += a0 * bq.w;
            acc[1][0] += a1 * bq.x; acc[1][1] += a1 * bq.y; acc[1][2] += a1 * bq.z; acc[1][3] += a1 * bq.w;
            acc[2][0] += a2 * bq.x; acc[2][1] += a2 * bq.y; acc[2][2] += a2 * bq.z; acc[2][3] += a2 * bq.w;
            acc[3][0] += a3 * bq.x; acc[3][1] += a3 * bq.y; acc[3][2] += a3 * bq.z; acc[3][3] += a3 * bq.w;
        }
        __syncthreads();
    }

    if (bx < 16) {
#pragma unroll
        for (int i = 0; i < 4; ++i)
            *(float4*)&Qout[(size_t)(m0 + 4 * ty + i) * EMB + n0 + 4 * tx] =
                make_float4(acc[i][0], acc[i][1], acc[i][2], acc[i][3]);
    } else if (bx == 16) {
#pragma unroll
        for (int i = 0; i < 4; ++i) {
            ushort4 u; u.x = f2bf(acc[i][0]); u.y = f2bf(acc[i][1]);
            u.z = f2bf(acc[i][2]); u.w = f2bf(acc[i][3]);
            *(ushort4*)&Kbf[(size_t)(m0 + 4 * ty + i) * HD + 4 * tx] = u;
        }
    } else {
#pragma unroll
        for (int j = 0; j < 4; ++j) {
            ushort4 u; u.x = f2bf(acc[0][j]); u.y = f2bf(acc[1][j]);
            u.z = f2bf(acc[2][j]); u.w = f2bf(acc[3][j]);
            *(ushort4*)&Vtbf[(size_t)(4 * tx + j) * NROW + m0 + 4 * ty] = u;
        }
    }
}

extern "C" void kernel_launch(void* const* d_in, const int* in_sizes, int n_in,
                              void* d_out, int out_size, void* d_ws, size_t ws_size,
                              hipStream_t stream) {
    const float* X  = (const float*)d_in[0];
    const float* Wq = (const float*)d_in[1];
    const float* Wk = (const float*)d_in[2];
    const float* Wv = (const float*)d_in[3];
    float* OutP = (float*)d_out;

    // ws layout (11.5 MiB):
    //   Xbf  [4096][1024] bf16   8 MiB  @ 0
    //   Wqt  [1024][1024] bf16   2 MiB  @ 8 MiB
    //   Wkt  [64][1024]   bf16 128 KiB  @ 10 MiB
    //   Wvt  [64][1024]   bf16 128 KiB  @ 10.25 MiB
    //   Kbf  [4096][64]   bf16 512 KiB  @ 10.5 MiB
    //   Vtbf [64][4096]   bf16 512 KiB  @ 11 MiB
    char* ws = (char*)d_ws;
    const size_t MB = 1024 * 1024;
    uint16_t* Xbf  = (uint16_t*)(ws);
    uint16_t* Wqt  = (uint16_t*)(ws + 8 * MB);
    uint16_t* Wkt  = (uint16_t*)(ws + 10 * MB);
    uint16_t* Wvt  = (uint16_t*)(ws + 10 * MB + 256 * 1024);
    uint16_t* Kbf  = (uint16_t*)(ws + 10 * MB + 512 * 1024);
    uint16_t* Vtbf = (uint16_t*)(ws + 11 * MB);

    if (ws_size >= 12 * MB) {
        prep<<<2336, 256, 0, stream>>>(X, Xbf, Wq, Wk, Wv, Wqt, Wkt, Wvt);
        qkv_gemm_mfma5<<<dim3(9, 64), 256, 0, stream>>>(Xbf, Wqt, Wkt, Wvt,
                                                        OutP, Kbf, Vtbf);
        mqa_attn<<<dim3(16, NH, BSZ), 256, 0, stream>>>(Kbf, Vtbf, OutP);
    } else {
        uint16_t* KbfS  = (uint16_t*)d_ws;
        uint16_t* VtbfS = KbfS + (size_t)NROW * HD;
        qkv_gemm_vec<<<dim3(18, 64), 256, 0, stream>>>(X, Wq, Wk, Wv, OutP, KbfS, VtbfS);
        mqa_attn<<<dim3(16, NH, BSZ), 256, 0, stream>>>(KbfS, VtbfS, OutP);
    }
}

// Round 10
// 131.189 us; speedup vs baseline: 1.1581x; 1.0076x over previous
//
#include <hip/hip_runtime.h>
#include <stdint.h>

#define NH   16
#define EMB  1024
#define HD   64
#define BSZ  2
#define SEQ  2048
#define NROW (BSZ * SEQ)          // 4096

typedef __attribute__((ext_vector_type(8))) short bf16x8;   // 8 bf16 = 4 VGPRs
typedef __attribute__((ext_vector_type(4))) float f32x4;    // MFMA C/D

__device__ __forceinline__ uint16_t f2bf(float f) {
    union { float f; uint32_t i; } v; v.f = f;
    uint32_t r = v.i + 0x7FFFu + ((v.i >> 16) & 1u);  // RNE
    return (uint16_t)(r >> 16);
}
__device__ __forceinline__ uint32_t pack2(float a, float b) {
    return (uint32_t)f2bf(a) | ((uint32_t)f2bf(b) << 16);
}
// single-instruction packed f32->bf16 (lo=a, hi=b), RNE
__device__ __forceinline__ uint32_t cvtpk(float a, float b) {
    uint32_t r;
    asm("v_cvt_pk_bf16_f32 %0, %1, %2" : "=v"(r) : "v"(a), "v"(b));
    return r;
}

// async global->LDS, 16 B per lane, wave-uniform LDS base
__device__ __forceinline__ void gl2lds16(const uint16_t* g, uint16_t* l) {
    __builtin_amdgcn_global_load_lds(
        static_cast<const uint32_t*>(static_cast<const void*>(g)),
        static_cast<uint32_t*>(static_cast<void*>(l)), 16, 0, 0);
}

// =====================================================================
// Prep (fused): blocks 0..2047 convert X fp32->bf16;
// blocks 2048..2335 transpose W fp32 [k][n] -> bf16 Wt[n][k].
// =====================================================================
__global__ __launch_bounds__(256) void prep(
    const float* __restrict__ X, uint16_t* __restrict__ Xbf,
    const float* __restrict__ Wq, const float* __restrict__ Wk,
    const float* __restrict__ Wv, uint16_t* __restrict__ Wqt,
    uint16_t* __restrict__ Wkt, uint16_t* __restrict__ Wvt)
{
    __shared__ uint16_t T[64][72];
    const int tid = threadIdx.x;
    if (blockIdx.x < 2048) {
        size_t idx = ((size_t)blockIdx.x * 256 + tid) * 8;
        float4 a = *(const float4*)&X[idx];
        float4 b = *(const float4*)&X[idx + 4];
        *(uint4*)&Xbf[idx] = make_uint4(pack2(a.x, a.y), pack2(a.z, a.w),
                                        pack2(b.x, b.y), pack2(b.z, b.w));
        return;
    }
    const int id = blockIdx.x - 2048;
    const float* W; uint16_t* Wt; int k0, n0, ldw;
    if (id < 256)      { W = Wq; Wt = Wqt; k0 = (id >> 4) * 64; n0 = (id & 15) * 64; ldw = EMB; }
    else if (id < 272) { W = Wk; Wt = Wkt; k0 = (id - 256) * 64; n0 = 0; ldw = HD; }
    else               { W = Wv; Wt = Wvt; k0 = (id - 272) * 64; n0 = 0; ldw = HD; }

    const int r = tid >> 2, c4 = (tid & 3) * 16;
#pragma unroll
    for (int i = 0; i < 4; ++i) {
        float4 wv = *(const float4*)&W[(size_t)(k0 + r) * ldw + n0 + c4 + 4 * i];
        T[r][c4 + 4 * i + 0] = f2bf(wv.x); T[r][c4 + 4 * i + 1] = f2bf(wv.y);
        T[r][c4 + 4 * i + 2] = f2bf(wv.z); T[r][c4 + 4 * i + 3] = f2bf(wv.w);
    }
    __syncthreads();
    const int n = tid >> 2, kk = (tid & 3) * 16;
    uint32_t o[8];
#pragma unroll
    for (int i = 0; i < 8; ++i)
        o[i] = (uint32_t)T[kk + 2 * i][n] | ((uint32_t)T[kk + 2 * i + 1][n] << 16);
    uint16_t* dst = &Wt[(size_t)(n0 + n) * EMB + k0 + kk];
    *(uint4*)dst       = make_uint4(o[0], o[1], o[2], o[3]);
    *(uint4*)(dst + 8) = make_uint4(o[4], o[5], o[6], o[7]);
}

// =====================================================================
// Kernel 1: MFMA projection GEMM v5 + XCD-chunked block swizzle.
// 64M x 128N, BK=64, grid (9, 64) = 576 blocks = 8 XCDs x 72.
// lin2 = (lin%8)*72 + lin/8 is bijective (576 = 8*72): each XCD gets
// 8 contiguous m-panels (1 MB A) + B (2.25 MB) -> fits 4 MB L2,
// converting ~72 MB of L3 A-re-reads into L2 hits.
// =====================================================================
__global__ __launch_bounds__(256) void qkv_gemm_mfma5(
    const uint16_t* __restrict__ Xbf, const uint16_t* __restrict__ Wqt,
    const uint16_t* __restrict__ Wkt, const uint16_t* __restrict__ Wvt,
    float* __restrict__ Qout, uint16_t* __restrict__ Kbf,
    uint16_t* __restrict__ Vtbf)
{
    const int tid  = threadIdx.x;
    const int w    = tid >> 6, lane = tid & 63;
    const int l    = lane & 15, quad = lane >> 4;
    const int wm   = w & 1, wn = w >> 1;      // wave: 32m x 64n quadrant

    // ---- XCD-chunked swizzle (bijective on 0..575) ----
    const int lin  = blockIdx.x + 9 * blockIdx.y;
    const int lin2 = (lin & 7) * 72 + (lin >> 3);
    const int nt   = lin2 % 9;
    const int m0   = (lin2 / 9) * 64;

    __shared__ uint16_t As[2][64 * 64];    // 8 KB per buffer
    __shared__ uint16_t Bs[2][128 * 64];   // 16 KB per buffer

    const uint16_t* gA[2]; uint32_t ldsA[2];
    const uint16_t* gB[4]; uint32_t ldsB[4];
#pragma unroll
    for (int i = 0; i < 2; ++i) {
        int G = (w * 2 + i) * 64 + lane;
        int r = G >> 3, cg = (G & 7) ^ (r & 7);
        gA[i] = &Xbf[(size_t)(m0 + r) * EMB + cg * 8];
        ldsA[i] = (w * 2 + i) * 512;              // elems, wave-uniform
    }
#pragma unroll
    for (int i = 0; i < 4; ++i) {
        int G = (w * 4 + i) * 64 + lane;
        int r = G >> 3, cg = (G & 7) ^ (r & 7);
        const uint16_t* bs;
        if (nt < 8)      bs = &Wqt[(size_t)(nt * 128 + r) * EMB + cg * 8];
        else if (r < 64) bs = &Wkt[(size_t)r * EMB + cg * 8];
        else             bs = &Wvt[(size_t)(r - 64) * EMB + cg * 8];
        gB[i] = bs;
        ldsB[i] = (w * 4 + i) * 512;
    }

    uint32_t offA[2][2], offB[4][2];
#pragma unroll
    for (int i = 0; i < 2; ++i)
#pragma unroll
        for (int kh = 0; kh < 2; ++kh) {
            int row = 32 * wm + 16 * i + l;
            offA[i][kh] = row * 64 + (((kh * 4 + quad) ^ (row & 7)) * 8);
        }
#pragma unroll
    for (int j = 0; j < 4; ++j)
#pragma unroll
        for (int kh = 0; kh < 2; ++kh) {
            int row = 64 * wn + 16 * j + l;
            offB[j][kh] = row * 64 + (((kh * 4 + quad) ^ (row & 7)) * 8);
        }

    f32x4 acc[2][4] = {};

#pragma unroll
    for (int i = 0; i < 2; ++i) { gl2lds16(gA[i], &As[0][ldsA[i]]); gA[i] += 64; }
#pragma unroll
    for (int i = 0; i < 4; ++i) { gl2lds16(gB[i], &Bs[0][ldsB[i]]); gB[i] += 64; }
    __syncthreads();

    for (int ks = 0; ks < 16; ++ks) {
        const int cur = ks & 1, nxt = cur ^ 1;
        if (ks < 15) {
#pragma unroll
            for (int i = 0; i < 2; ++i) { gl2lds16(gA[i], &As[nxt][ldsA[i]]); gA[i] += 64; }
#pragma unroll
            for (int i = 0; i < 4; ++i) { gl2lds16(gB[i], &Bs[nxt][ldsB[i]]); gB[i] += 64; }
        }
#pragma unroll
        for (int kh = 0; kh < 2; ++kh) {
            bf16x8 af[2], bfr[4];
#pragma unroll
            for (int i = 0; i < 2; ++i) af[i] = *(const bf16x8*)&As[cur][offA[i][kh]];
#pragma unroll
            for (int j = 0; j < 4; ++j) bfr[j] = *(const bf16x8*)&Bs[cur][offB[j][kh]];
#pragma unroll
            for (int i = 0; i < 2; ++i)
#pragma unroll
                for (int j = 0; j < 4; ++j)
                    acc[i][j] = __builtin_amdgcn_mfma_f32_16x16x32_bf16(
                        af[i], bfr[j], acc[i][j], 0, 0, 0);
        }
        __syncthreads();
    }

    if (nt < 8) {             // Q -> fp32 d_out
#pragma unroll
        for (int i = 0; i < 2; ++i)
#pragma unroll
            for (int j = 0; j < 4; ++j)
#pragma unroll
                for (int r = 0; r < 4; ++r)
                    Qout[(size_t)(m0 + 32 * wm + 16 * i + 4 * quad + r) * EMB
                         + nt * 128 + 64 * wn + 16 * j + l] = acc[i][j][r];
    } else if (wn == 0) {     // K -> bf16 [t][d]
#pragma unroll
        for (int i = 0; i < 2; ++i)
#pragma unroll
            for (int j = 0; j < 4; ++j)
#pragma unroll
                for (int r = 0; r < 4; ++r)
                    Kbf[(size_t)(m0 + 32 * wm + 16 * i + 4 * quad + r) * HD
                        + 16 * j + l] = f2bf(acc[i][j][r]);
    } else {                  // V -> bf16 transposed [d][t]
#pragma unroll
        for (int i = 0; i < 2; ++i)
#pragma unroll
            for (int j = 0; j < 4; ++j)
#pragma unroll
                for (int r = 0; r < 4; ++r)
                    Vtbf[(size_t)(16 * j + l) * NROW
                         + m0 + 32 * wm + 16 * i + 4 * quad + r] = f2bf(acc[i][j][r]);
    }
}

// =====================================================================
// Kernel 2: causal MQA flash attention, COMPLEMENTARY-PAIR blocks
// (R8-proven, 132.2 us total): exactly 33 bodies/block = perfect
// static balance under full residency.  DMA staging with pre-swizzled
// sources (pi-K rows + XOR granule swizzle, conflicts=0), in-register
// P, MFMA row-sum denominator.  Grid (16, NH, BSZ) = 512 blocks.
// =====================================================================
__global__ __launch_bounds__(256) void mqa_attn(
    const uint16_t* __restrict__ Kbf, const uint16_t* __restrict__ Vtbf,
    float* __restrict__ Out)
{
    const int tid  = threadIdx.x;
    const int w    = tid >> 6;
    const int lane = tid & 63;
    const int l    = lane & 15;
    const int quad = lane >> 4;
    const int i  = blockIdx.x;            // 0..15 (i=0 longest)
    const int h  = blockIdx.y, b = blockIdx.z;
    const int qt0 = 31 - i, qt1 = i;      // big, small q-tile
    const int q00 = qt0 * 64, q01 = qt1 * 64;

    __shared__ __align__(16) uint16_t Ks[2][4096];  // K dbuf (pi rows, swz)
    __shared__ __align__(16) uint16_t Vs[2][4096];  // V^T dbuf (swz)
    __shared__ __align__(16) uint16_t Ps[2][64][72];   // Q staging

    const float C = 0.125f * 1.4426950408889634f;      // scale * log2e
    const int sr = tid >> 2, sc = (tid & 3) * 16;

    // ---- DMA staging sources: slot = w*2+i2; LDS granule (r,g) holds
    //      K row pi(r) col-granule g^(r&7);  V^T row r col g^(r&7).
    const uint16_t* kSrc[2]; const uint16_t* vSrc[2]; uint32_t dstE[2];
#pragma unroll
    for (int i2 = 0; i2 < 2; ++i2) {
        int G = (w * 2 + i2) * 64 + lane;
        int r = G >> 3, g = G & 7;
        int pr = (r & 32) + ((r >> 2) & 3) * 8 + ((r & 16) >> 2) + (r & 3);
        int cg = g ^ (r & 7);
        kSrc[i2] = &Kbf[(size_t)(b * SEQ + pr) * HD + cg * 8];
        vSrc[i2] = &Vtbf[(size_t)r * NROW + b * SEQ + cg * 8];
        dstE[i2] = (uint32_t)(w * 2 + i2) * 512;   // elems
    }

    // ---- stage tile 0 via DMA ----
#pragma unroll
    for (int i2 = 0; i2 < 2; ++i2) {
        gl2lds16(kSrc[i2], &Ks[0][dstE[i2]]);
        gl2lds16(vSrc[i2], &Vs[0][dstE[i2]]);
        kSrc[i2] += 64 * HD;   // next k-tile = +64 rows
        vSrc[i2] += 64;        // next k-tile = +64 cols
    }

    // ---- stage Q for both q-tiles (pre-scaled) into Ps ----
#pragma unroll
    for (int t = 0; t < 2; ++t) {
        const int q0t = t ? q01 : q00;
        const float* src = &Out[(size_t)(b * SEQ + q0t + sr) * EMB + h * HD + sc];
        float4 f0 = *(const float4*)(src + 0);
        float4 f1 = *(const float4*)(src + 4);
        float4 f2 = *(const float4*)(src + 8);
        float4 f3 = *(const float4*)(src + 12);
        *(uint4*)&Ps[t][sr][sc] =
            make_uint4(pack2(f0.x * C, f0.y * C), pack2(f0.z * C, f0.w * C),
                       pack2(f1.x * C, f1.y * C), pack2(f1.z * C, f1.w * C));
        *(uint4*)&Ps[t][sr][sc + 8] =
            make_uint4(pack2(f2.x * C, f2.y * C), pack2(f2.z * C, f2.w * C),
                       pack2(f3.x * C, f3.y * C), pack2(f3.z * C, f3.w * C));
    }
    __syncthreads();   // drains DMA (vmcnt) + Q writes

    // ---- Q B-fragments for both q-tiles ----
    bf16x8 qf[2][2];
#pragma unroll
    for (int t = 0; t < 2; ++t) {
        qf[t][0] = *(const bf16x8*)&Ps[t][16 * w + l][quad * 8];
        qf[t][1] = *(const bf16x8*)&Ps[t][16 * w + l][32 + quad * 8];
    }

    // ---- loop-invariant LDS read offsets (same for Ks and Vs) ----
    uint32_t off[4][2];
#pragma unroll
    for (int ts = 0; ts < 4; ++ts)
#pragma unroll
        for (int kh = 0; kh < 2; ++kh)
            off[ts][kh] = (16 * ts + l) * 64 + (((4 * kh + quad) ^ (l & 7)) * 8);

    bf16x8 ones;
#pragma unroll
    for (int j = 0; j < 8; ++j) ones[j] = (short)0x3F80;   // bf16 1.0

    f32x4 accO[2][4] = {};
    f32x4 accSum[2] = {};
    const int qi_l = 16 * w + l;

    // ---- one k-tile step; DO1/M0/M1 compile-time at each call site ----
    auto body = [&](int kb, bool DO1, bool M0, bool M1) __attribute__((always_inline)) {
        const int cur = kb & 1, nxt = cur ^ 1;

        // K / V fragments from LDS (swizzled)
        bf16x8 ka[4][2], vb[4][2];
#pragma unroll
        for (int ts = 0; ts < 4; ++ts) {
            ka[ts][0] = *(const bf16x8*)&Ks[cur][off[ts][0]];
            ka[ts][1] = *(const bf16x8*)&Ks[cur][off[ts][1]];
            vb[ts][0] = *(const bf16x8*)&Vs[cur][off[ts][0]];
            vb[ts][1] = *(const bf16x8*)&Vs[cur][off[ts][1]];
        }

        // DMA-stage tile kb+1 into idle buffers
        if (kb < qt0) {
#pragma unroll
            for (int i2 = 0; i2 < 2; ++i2) {
                gl2lds16(kSrc[i2], &Ks[nxt][dstE[i2]]);
                gl2lds16(vSrc[i2], &Vs[nxt][dstE[i2]]);
                kSrc[i2] += 64 * HD;
                vSrc[i2] += 64;
            }
        }

        // QK^T for both tiles
        f32x4 accS0[4] = {}, accS1[4] = {};
#pragma unroll
        for (int ts = 0; ts < 4; ++ts) {
            accS0[ts] = __builtin_amdgcn_mfma_f32_16x16x32_bf16(ka[ts][0], qf[0][0], accS0[ts], 0, 0, 0);
            accS0[ts] = __builtin_amdgcn_mfma_f32_16x16x32_bf16(ka[ts][1], qf[0][1], accS0[ts], 0, 0, 0);
        }
        if (DO1) {
#pragma unroll
            for (int ts = 0; ts < 4; ++ts) {
                accS1[ts] = __builtin_amdgcn_mfma_f32_16x16x32_bf16(ka[ts][0], qf[1][0], accS1[ts], 0, 0, 0);
                accS1[ts] = __builtin_amdgcn_mfma_f32_16x16x32_bf16(ka[ts][1], qf[1][1], accS1[ts], 0, 0, 0);
            }
        }

        // tile 0: exp2 / mask / in-register pa build / PV
        {
            float pv[16];
#pragma unroll
            for (int ts = 0; ts < 4; ++ts)
#pragma unroll
                for (int r = 0; r < 4; ++r)
                    pv[4 * ts + r] = exp2f(accS0[ts][r]);
            if (M0) {
                // k-position of pv[4ts+r] is 32(ts>=2) + 8quad + 4(ts&1) + r
#pragma unroll
                for (int ts = 0; ts < 4; ++ts)
#pragma unroll
                    for (int r = 0; r < 4; ++r)
                        if ((((ts & 2) << 4) + ((ts & 1) << 2) + 8 * quad + r) > qi_l)
                            pv[4 * ts + r] = 0.f;
            }
            union { uint32_t u[4]; bf16x8 v; } A0, A1;
#pragma unroll
            for (int j = 0; j < 4; ++j) A0.u[j] = cvtpk(pv[2 * j],     pv[2 * j + 1]);
#pragma unroll
            for (int j = 0; j < 4; ++j) A1.u[j] = cvtpk(pv[8 + 2 * j], pv[9 + 2 * j]);
#pragma unroll
            for (int tn = 0; tn < 4; ++tn) {
                accO[0][tn] = __builtin_amdgcn_mfma_f32_16x16x32_bf16(A0.v, vb[tn][0], accO[0][tn], 0, 0, 0);
                accO[0][tn] = __builtin_amdgcn_mfma_f32_16x16x32_bf16(A1.v, vb[tn][1], accO[0][tn], 0, 0, 0);
            }
            accSum[0] = __builtin_amdgcn_mfma_f32_16x16x32_bf16(A0.v, ones, accSum[0], 0, 0, 0);
            accSum[0] = __builtin_amdgcn_mfma_f32_16x16x32_bf16(A1.v, ones, accSum[0], 0, 0, 0);
        }
        // tile 1
        if (DO1) {
            float pv[16];
#pragma unroll
            for (int ts = 0; ts < 4; ++ts)
#pragma unroll
                for (int r = 0; r < 4; ++r)
                    pv[4 * ts + r] = exp2f(accS1[ts][r]);
            if (M1) {
#pragma unroll
                for (int ts = 0; ts < 4; ++ts)
#pragma unroll
                    for (int r = 0; r < 4; ++r)
                        if ((((ts & 2) << 4) + ((ts & 1) << 2) + 8 * quad + r) > qi_l)
                            pv[4 * ts + r] = 0.f;
            }
            union { uint32_t u[4]; bf16x8 v; } A0, A1;
#pragma unroll
            for (int j = 0; j < 4; ++j) A0.u[j] = cvtpk(pv[2 * j],     pv[2 * j + 1]);
#pragma unroll
            for (int j = 0; j < 4; ++j) A1.u[j] = cvtpk(pv[8 + 2 * j], pv[9 + 2 * j]);
#pragma unroll
            for (int tn = 0; tn < 4; ++tn) {
                accO[1][tn] = __builtin_amdgcn_mfma_f32_16x16x32_bf16(A0.v, vb[tn][0], accO[1][tn], 0, 0, 0);
                accO[1][tn] = __builtin_amdgcn_mfma_f32_16x16x32_bf16(A1.v, vb[tn][1], accO[1][tn], 0, 0, 0);
            }
            accSum[1] = __builtin_amdgcn_mfma_f32_16x16x32_bf16(A0.v, ones, accSum[1], 0, 0, 0);
            accSum[1] = __builtin_amdgcn_mfma_f32_16x16x32_bf16(A1.v, ones, accSum[1], 0, 0, 0);
        }

        if (kb < qt0) __syncthreads();   // [cur] reads done; DMA for nxt drained
    };

    // ---- segmented k-loop: branch-free bodies, peeled diagonals ----
    for (int kb = 0; kb < qt1; ++kb) body(kb, true,  false, false);
    body(qt1, true,  false, true);                 // tile-1 diagonal
    for (int kb = qt1 + 1; kb < qt0; ++kb) body(kb, false, false, false);
    body(qt0, false, true,  false);                // tile-0 diagonal

    // ---- epilogue: denominator lane-aligned with accO rows ----
#pragma unroll
    for (int t = 0; t < 2; ++t) {
        const int q0t = t ? q01 : q00;
#pragma unroll
        for (int r = 0; r < 4; ++r) {
            float invr = 1.0f / accSum[t][r];
            const int row = q0t + 16 * w + 4 * quad + r;
#pragma unroll
            for (int tn = 0; tn < 4; ++tn)
                Out[(size_t)(b * SEQ + row) * EMB + h * HD + 16 * tn + l] =
                    accO[t][tn][r] * invr;
        }
    }
}

// =====================================================================
// Fallback (proven): fp32 vector GEMM (writes same layouts).
// =====================================================================
__global__ __launch_bounds__(256) void qkv_gemm_vec(
    const float* __restrict__ X,  const float* __restrict__ Wq,
    const float* __restrict__ Wk, const float* __restrict__ Wv,
    float* __restrict__ Qout, uint16_t* __restrict__ Kbf,
    uint16_t* __restrict__ Vtbf)
{
    const int tid = threadIdx.x;
    const int tx = tid & 15, ty = tid >> 4;
    const int bx = blockIdx.x;
    const int m0 = blockIdx.y * 64;

    const float* W; int ldw, n0;
    if (bx < 16)       { W = Wq; ldw = EMB; n0 = bx * 64; }
    else if (bx == 16) { W = Wk; ldw = HD;  n0 = 0; }
    else               { W = Wv; ldw = HD;  n0 = 0; }

    __shared__ float sA[64][17];
    __shared__ float sB[16][64];

    float acc[4][4] = {};
    const int arow = tid >> 2, acol = (tid & 3) * 4;
    const int brow = tid >> 4, bcol = (tid & 15) * 4;

    for (int k0 = 0; k0 < EMB; k0 += 16) {
        float4 fa = *(const float4*)&X[(size_t)(m0 + arow) * EMB + k0 + acol];
        float4 fb = *(const float4*)&W[(size_t)(k0 + brow) * ldw + n0 + bcol];
        sA[arow][acol + 0] = fa.x; sA[arow][acol + 1] = fa.y;
        sA[arow][acol + 2] = fa.z; sA[arow][acol + 3] = fa.w;
        sB[brow][bcol + 0] = fb.x; sB[brow][bcol + 1] = fb.y;
        sB[brow][bcol + 2] = fb.z; sB[brow][bcol + 3] = fb.w;
        __syncthreads();
#pragma unroll
        for (int kk = 0; kk < 16; ++kk) {
            float a0 = sA[4 * ty + 0][kk];
            float a1 = sA[4 * ty + 1][kk];
            float a2 = sA[4 * ty + 2][kk];
            float a3 = sA[4 * ty + 3][kk];
            float4 bq = *(const float4*)&sB[kk][4 * tx];
            acc[0][0] += a0 * bq.x; acc[0][1] += a0 * bq.y; acc[0][2] += a0 * bq.z; acc[0][3] += a0 * bq.w;
            acc[1][0] += a1 * bq.x; acc[1][1] += a1 * bq.y; acc[1][2] += a1 * bq.z; acc[1][3] += a1 * bq.w;
            acc[2][0] += a2 * bq.x; acc[2][1] += a2 * bq.y; acc[2][2] += a2 * bq.z; acc[2][3] += a2 * bq.w;
            acc[3][0] += a3 * bq.x; acc[3][1] += a3 * bq.y; acc[3][2] += a3 * bq.z; acc[3][3] += a3 * bq.w;
        }
        __syncthreads();
    }

    if (bx < 16) {
#pragma unroll
        for (int i = 0; i < 4; ++i)
            *(float4*)&Qout[(size_t)(m0 + 4 * ty + i) * EMB + n0 + 4 * tx] =
                make_float4(acc[i][0], acc[i][1], acc[i][2], acc[i][3]);
    } else if (bx == 16) {
#pragma unroll
        for (int i = 0; i < 4; ++i) {
            ushort4 u; u.x = f2bf(acc[i][0]); u.y = f2bf(acc[i][1]);
            u.z = f2bf(acc[i][2]); u.w = f2bf(acc[i][3]);
            *(ushort4*)&Kbf[(size_t)(m0 + 4 * ty + i) * HD + 4 * tx] = u;
        }
    } else {
#pragma unroll
        for (int j = 0; j < 4; ++j) {
            ushort4 u; u.x = f2bf(acc[0][j]); u.y = f2bf(acc[1][j]);
            u.z = f2bf(acc[2][j]); u.w = f2bf(acc[3][j]);
            *(ushort4*)&Vtbf[(size_t)(4 * tx + j) * NROW + m0 + 4 * ty] = u;
        }
    }
}

extern "C" void kernel_launch(void* const* d_in, const int* in_sizes, int n_in,
                              void* d_out, int out_size, void* d_ws, size_t ws_size,
                              hipStream_t stream) {
    const float* X  = (const float*)d_in[0];
    const float* Wq = (const float*)d_in[1];
    const float* Wk = (const float*)d_in[2];
    const float* Wv = (const float*)d_in[3];
    float* OutP = (float*)d_out;

    // ws layout (11.5 MiB):
    //   Xbf  [4096][1024] bf16   8 MiB  @ 0
    //   Wqt  [1024][1024] bf16   2 MiB  @ 8 MiB
    //   Wkt  [64][1024]   bf16 128 KiB  @ 10 MiB
    //   Wvt  [64][1024]   bf16 128 KiB  @ 10.25 MiB
    //   Kbf  [4096][64]   bf16 512 KiB  @ 10.5 MiB
    //   Vtbf [64][4096]   bf16 512 KiB  @ 11 MiB
    char* ws = (char*)d_ws;
    const size_t MB = 1024 * 1024;
    uint16_t* Xbf  = (uint16_t*)(ws);
    uint16_t* Wqt  = (uint16_t*)(ws + 8 * MB);
    uint16_t* Wkt  = (uint16_t*)(ws + 10 * MB);
    uint16_t* Wvt  = (uint16_t*)(ws + 10 * MB + 256 * 1024);
    uint16_t* Kbf  = (uint16_t*)(ws + 10 * MB + 512 * 1024);
    uint16_t* Vtbf = (uint16_t*)(ws + 11 * MB);

    if (ws_size >= 12 * MB) {
        prep<<<2336, 256, 0, stream>>>(X, Xbf, Wq, Wk, Wv, Wqt, Wkt, Wvt);
        qkv_gemm_mfma5<<<dim3(9, 64), 256, 0, stream>>>(Xbf, Wqt, Wkt, Wvt,
                                                        OutP, Kbf, Vtbf);
        mqa_attn<<<dim3(16, NH, BSZ), 256, 0, stream>>>(Kbf, Vtbf, OutP);
    } else {
        uint16_t* KbfS  = (uint16_t*)d_ws;
        uint16_t* VtbfS = KbfS + (size_t)NROW * HD;
        qkv_gemm_vec<<<dim3(18, 64), 256, 0, stream>>>(X, Wq, Wk, Wv, OutP, KbfS, VtbfS);
        mqa_attn<<<dim3(16, NH, BSZ), 256, 0, stream>>>(KbfS, VtbfS, OutP);
    }
}

// Round 11
// 128.838 us; speedup vs baseline: 1.1793x; 1.0182x over previous
//
#include <hip/hip_runtime.h>
#include <stdint.h>

#define NH   16
#define EMB  1024
#define HD   64
#define BSZ  2
#define SEQ  2048
#define NROW (BSZ * SEQ)          // 4096

typedef __attribute__((ext_vector_type(8))) short bf16x8;   // 8 bf16 = 4 VGPRs
typedef __attribute__((ext_vector_type(4))) float f32x4;    // MFMA C/D

#define CQ 0.18033688011112042f   // 0.125 * log2(e), folded into Wq

__device__ __forceinline__ uint16_t f2bf(float f) {
    union { float f; uint32_t i; } v; v.f = f;
    uint32_t r = v.i + 0x7FFFu + ((v.i >> 16) & 1u);  // RNE
    return (uint16_t)(r >> 16);
}
__device__ __forceinline__ uint32_t pack2(float a, float b) {
    return (uint32_t)f2bf(a) | ((uint32_t)f2bf(b) << 16);
}
// single-instruction packed f32->bf16 (lo=a, hi=b), RNE
__device__ __forceinline__ uint32_t cvtpk(float a, float b) {
    uint32_t r;
    asm("v_cvt_pk_bf16_f32 %0, %1, %2" : "=v"(r) : "v"(a), "v"(b));
    return r;
}

// async global->LDS, 16 B per lane, wave-uniform LDS base
__device__ __forceinline__ void gl2lds16(const uint16_t* g, uint16_t* l) {
    __builtin_amdgcn_global_load_lds(
        static_cast<const uint32_t*>(static_cast<const void*>(g)),
        static_cast<uint32_t*>(static_cast<void*>(l)), 16, 0, 0);
}

// =====================================================================
// Prep (fused): blocks 0..2047 convert X fp32->bf16;
// blocks 2048..2335 transpose W fp32 [k][n] -> bf16 Wt[n][k].
// R21: Wq is PRE-SCALED by CQ (softmax scale * log2e) so Q comes out
// of the GEMM already scaled -> attn consumes Q as raw bf16.
// =====================================================================
__global__ __launch_bounds__(256) void prep(
    const float* __restrict__ X, uint16_t* __restrict__ Xbf,
    const float* __restrict__ Wq, const float* __restrict__ Wk,
    const float* __restrict__ Wv, uint16_t* __restrict__ Wqt,
    uint16_t* __restrict__ Wkt, uint16_t* __restrict__ Wvt)
{
    __shared__ uint16_t T[64][72];
    const int tid = threadIdx.x;
    if (blockIdx.x < 2048) {
        size_t idx = ((size_t)blockIdx.x * 256 + tid) * 8;
        float4 a = *(const float4*)&X[idx];
        float4 b = *(const float4*)&X[idx + 4];
        *(uint4*)&Xbf[idx] = make_uint4(pack2(a.x, a.y), pack2(a.z, a.w),
                                        pack2(b.x, b.y), pack2(b.z, b.w));
        return;
    }
    const int id = blockIdx.x - 2048;
    const float* W; uint16_t* Wt; int k0, n0, ldw;
    if (id < 256)      { W = Wq; Wt = Wqt; k0 = (id >> 4) * 64; n0 = (id & 15) * 64; ldw = EMB; }
    else if (id < 272) { W = Wk; Wt = Wkt; k0 = (id - 256) * 64; n0 = 0; ldw = HD; }
    else               { W = Wv; Wt = Wvt; k0 = (id - 272) * 64; n0 = 0; ldw = HD; }
    const float scl = (id < 256) ? CQ : 1.0f;

    const int r = tid >> 2, c4 = (tid & 3) * 16;
#pragma unroll
    for (int i = 0; i < 4; ++i) {
        float4 wv = *(const float4*)&W[(size_t)(k0 + r) * ldw + n0 + c4 + 4 * i];
        T[r][c4 + 4 * i + 0] = f2bf(wv.x * scl); T[r][c4 + 4 * i + 1] = f2bf(wv.y * scl);
        T[r][c4 + 4 * i + 2] = f2bf(wv.z * scl); T[r][c4 + 4 * i + 3] = f2bf(wv.w * scl);
    }
    __syncthreads();
    const int n = tid >> 2, kk = (tid & 3) * 16;
    uint32_t o[8];
#pragma unroll
    for (int i = 0; i < 8; ++i)
        o[i] = (uint32_t)T[kk + 2 * i][n] | ((uint32_t)T[kk + 2 * i + 1][n] << 16);
    uint16_t* dst = &Wt[(size_t)(n0 + n) * EMB + k0 + kk];
    *(uint4*)dst       = make_uint4(o[0], o[1], o[2], o[3]);
    *(uint4*)(dst + 8) = make_uint4(o[4], o[5], o[6], o[7]);
}

// =====================================================================
// Kernel 1: MFMA projection GEMM v5 + XCD-chunked block swizzle
// (R10-proven).  R21: Q written as BF16 to workspace Qbf (half the
// store bytes; attn DMA-stages it directly).
// =====================================================================
__global__ __launch_bounds__(256) void qkv_gemm_mfma5(
    const uint16_t* __restrict__ Xbf, const uint16_t* __restrict__ Wqt,
    const uint16_t* __restrict__ Wkt, const uint16_t* __restrict__ Wvt,
    uint16_t* __restrict__ Qbf, uint16_t* __restrict__ Kbf,
    uint16_t* __restrict__ Vtbf)
{
    const int tid  = threadIdx.x;
    const int w    = tid >> 6, lane = tid & 63;
    const int l    = lane & 15, quad = lane >> 4;
    const int wm   = w & 1, wn = w >> 1;      // wave: 32m x 64n quadrant

    // ---- XCD-chunked swizzle (bijective on 0..575) ----
    const int lin  = blockIdx.x + 9 * blockIdx.y;
    const int lin2 = (lin & 7) * 72 + (lin >> 3);
    const int nt   = lin2 % 9;
    const int m0   = (lin2 / 9) * 64;

    __shared__ uint16_t As[2][64 * 64];    // 8 KB per buffer
    __shared__ uint16_t Bs[2][128 * 64];   // 16 KB per buffer

    const uint16_t* gA[2]; uint32_t ldsA[2];
    const uint16_t* gB[4]; uint32_t ldsB[4];
#pragma unroll
    for (int i = 0; i < 2; ++i) {
        int G = (w * 2 + i) * 64 + lane;
        int r = G >> 3, cg = (G & 7) ^ (r & 7);
        gA[i] = &Xbf[(size_t)(m0 + r) * EMB + cg * 8];
        ldsA[i] = (w * 2 + i) * 512;              // elems, wave-uniform
    }
#pragma unroll
    for (int i = 0; i < 4; ++i) {
        int G = (w * 4 + i) * 64 + lane;
        int r = G >> 3, cg = (G & 7) ^ (r & 7);
        const uint16_t* bs;
        if (nt < 8)      bs = &Wqt[(size_t)(nt * 128 + r) * EMB + cg * 8];
        else if (r < 64) bs = &Wkt[(size_t)r * EMB + cg * 8];
        else             bs = &Wvt[(size_t)(r - 64) * EMB + cg * 8];
        gB[i] = bs;
        ldsB[i] = (w * 4 + i) * 512;
    }

    uint32_t offA[2][2], offB[4][2];
#pragma unroll
    for (int i = 0; i < 2; ++i)
#pragma unroll
        for (int kh = 0; kh < 2; ++kh) {
            int row = 32 * wm + 16 * i + l;
            offA[i][kh] = row * 64 + (((kh * 4 + quad) ^ (row & 7)) * 8);
        }
#pragma unroll
    for (int j = 0; j < 4; ++j)
#pragma unroll
        for (int kh = 0; kh < 2; ++kh) {
            int row = 64 * wn + 16 * j + l;
            offB[j][kh] = row * 64 + (((kh * 4 + quad) ^ (row & 7)) * 8);
        }

    f32x4 acc[2][4] = {};

#pragma unroll
    for (int i = 0; i < 2; ++i) { gl2lds16(gA[i], &As[0][ldsA[i]]); gA[i] += 64; }
#pragma unroll
    for (int i = 0; i < 4; ++i) { gl2lds16(gB[i], &Bs[0][ldsB[i]]); gB[i] += 64; }
    __syncthreads();

    for (int ks = 0; ks < 16; ++ks) {
        const int cur = ks & 1, nxt = cur ^ 1;
        if (ks < 15) {
#pragma unroll
            for (int i = 0; i < 2; ++i) { gl2lds16(gA[i], &As[nxt][ldsA[i]]); gA[i] += 64; }
#pragma unroll
            for (int i = 0; i < 4; ++i) { gl2lds16(gB[i], &Bs[nxt][ldsB[i]]); gB[i] += 64; }
        }
#pragma unroll
        for (int kh = 0; kh < 2; ++kh) {
            bf16x8 af[2], bfr[4];
#pragma unroll
            for (int i = 0; i < 2; ++i) af[i] = *(const bf16x8*)&As[cur][offA[i][kh]];
#pragma unroll
            for (int j = 0; j < 4; ++j) bfr[j] = *(const bf16x8*)&Bs[cur][offB[j][kh]];
#pragma unroll
            for (int i = 0; i < 2; ++i)
#pragma unroll
                for (int j = 0; j < 4; ++j)
                    acc[i][j] = __builtin_amdgcn_mfma_f32_16x16x32_bf16(
                        af[i], bfr[j], acc[i][j], 0, 0, 0);
        }
        __syncthreads();
    }

    if (nt < 8) {             // Q -> bf16 workspace (pre-scaled via Wqt)
#pragma unroll
        for (int i = 0; i < 2; ++i)
#pragma unroll
            for (int j = 0; j < 4; ++j)
#pragma unroll
                for (int r = 0; r < 4; ++r)
                    Qbf[(size_t)(m0 + 32 * wm + 16 * i + 4 * quad + r) * EMB
                        + nt * 128 + 64 * wn + 16 * j + l] = f2bf(acc[i][j][r]);
    } else if (wn == 0) {     // K -> bf16 [t][d]
#pragma unroll
        for (int i = 0; i < 2; ++i)
#pragma unroll
            for (int j = 0; j < 4; ++j)
#pragma unroll
                for (int r = 0; r < 4; ++r)
                    Kbf[(size_t)(m0 + 32 * wm + 16 * i + 4 * quad + r) * HD
                        + 16 * j + l] = f2bf(acc[i][j][r]);
    } else {                  // V -> bf16 transposed [d][t]
#pragma unroll
        for (int i = 0; i < 2; ++i)
#pragma unroll
            for (int j = 0; j < 4; ++j)
#pragma unroll
                for (int r = 0; r < 4; ++r)
                    Vtbf[(size_t)(16 * j + l) * NROW
                         + m0 + 32 * wm + 16 * i + 4 * quad + r] = f2bf(acc[i][j][r]);
    }
}

// =====================================================================
// Kernel 2: causal MQA flash attention, COMPLEMENTARY-PAIR blocks
// (R8/R10-proven core).  R21: Q arrives pre-scaled bf16 in Qbf and is
// DMA-staged into LDS with the same XOR-granule pre-swizzled-source
// machinery as K/V -- the whole fp32-load/scale/pack prologue is gone.
// Grid (16, NH, BSZ) = 512 blocks.
// =====================================================================
__global__ __launch_bounds__(256) void mqa_attn(
    const uint16_t* __restrict__ Qbf, const uint16_t* __restrict__ Kbf,
    const uint16_t* __restrict__ Vtbf, float* __restrict__ Out)
{
    const int tid  = threadIdx.x;
    const int w    = tid >> 6;
    const int lane = tid & 63;
    const int l    = lane & 15;
    const int quad = lane >> 4;
    const int i  = blockIdx.x;            // 0..15 (i=0 longest)
    const int h  = blockIdx.y, b = blockIdx.z;
    const int qt0 = 31 - i, qt1 = i;      // big, small q-tile
    const int q00 = qt0 * 64, q01 = qt1 * 64;

    __shared__ __align__(16) uint16_t Ks[2][4096];  // K dbuf (pi rows, swz)
    __shared__ __align__(16) uint16_t Vs[2][4096];  // V^T dbuf (swz)
    __shared__ __align__(16) uint16_t Ps[2][4096];  // Q tiles (swz)

    // ---- DMA staging sources: slot = w*2+i2; LDS granule (r,g) holds
    //      K row pi(r) col-granule g^(r&7);  V^T row r col g^(r&7).
    const uint16_t* kSrc[2]; const uint16_t* vSrc[2]; uint32_t dstE[2];
#pragma unroll
    for (int i2 = 0; i2 < 2; ++i2) {
        int G = (w * 2 + i2) * 64 + lane;
        int r = G >> 3, g = G & 7;
        int pr = (r & 32) + ((r >> 2) & 3) * 8 + ((r & 16) >> 2) + (r & 3);
        int cg = g ^ (r & 7);
        kSrc[i2] = &Kbf[(size_t)(b * SEQ + pr) * HD + cg * 8];
        vSrc[i2] = &Vtbf[(size_t)r * NROW + b * SEQ + cg * 8];
        dstE[i2] = (uint32_t)(w * 2 + i2) * 512;   // elems
    }

    // ---- stage K/V tile 0 + both Q tiles via DMA ----
#pragma unroll
    for (int i2 = 0; i2 < 2; ++i2) {
        gl2lds16(kSrc[i2], &Ks[0][dstE[i2]]);
        gl2lds16(vSrc[i2], &Vs[0][dstE[i2]]);
        kSrc[i2] += 64 * HD;   // next k-tile = +64 rows
        vSrc[i2] += 64;        // next k-tile = +64 cols
    }
#pragma unroll
    for (int t = 0; t < 2; ++t) {
        const int q0t = t ? q01 : q00;
#pragma unroll
        for (int i2 = 0; i2 < 2; ++i2) {
            int G = (w * 2 + i2) * 64 + lane;
            int r = G >> 3, g = G & 7;
            int cg = g ^ (r & 7);
            gl2lds16(&Qbf[(size_t)(b * SEQ + q0t + r) * EMB + h * HD + cg * 8],
                     &Ps[t][dstE[i2]]);
        }
    }
    __syncthreads();   // drains all DMA (vmcnt)

    // ---- Q B-fragments for both q-tiles (swizzled read) ----
    bf16x8 qf[2][2];
    {
        const int row = 16 * w + l;
#pragma unroll
        for (int t = 0; t < 2; ++t) {
            qf[t][0] = *(const bf16x8*)&Ps[t][row * 64 + (((0 + quad) ^ (row & 7)) * 8)];
            qf[t][1] = *(const bf16x8*)&Ps[t][row * 64 + (((4 + quad) ^ (row & 7)) * 8)];
        }
    }

    // ---- loop-invariant LDS read offsets (same for Ks and Vs) ----
    uint32_t off[4][2];
#pragma unroll
    for (int ts = 0; ts < 4; ++ts)
#pragma unroll
        for (int kh = 0; kh < 2; ++kh)
            off[ts][kh] = (16 * ts + l) * 64 + (((4 * kh + quad) ^ (l & 7)) * 8);

    bf16x8 ones;
#pragma unroll
    for (int j = 0; j < 8; ++j) ones[j] = (short)0x3F80;   // bf16 1.0

    f32x4 accO[2][4] = {};
    f32x4 accSum[2] = {};
    const int qi_l = 16 * w + l;

    // ---- one k-tile step; DO1/M0/M1 compile-time at each call site ----
    auto body = [&](int kb, bool DO1, bool M0, bool M1) __attribute__((always_inline)) {
        const int cur = kb & 1, nxt = cur ^ 1;

        // K / V fragments from LDS (swizzled)
        bf16x8 ka[4][2], vb[4][2];
#pragma unroll
        for (int ts = 0; ts < 4; ++ts) {
            ka[ts][0] = *(const bf16x8*)&Ks[cur][off[ts][0]];
            ka[ts][1] = *(const bf16x8*)&Ks[cur][off[ts][1]];
            vb[ts][0] = *(const bf16x8*)&Vs[cur][off[ts][0]];
            vb[ts][1] = *(const bf16x8*)&Vs[cur][off[ts][1]];
        }

        // DMA-stage tile kb+1 into idle buffers
        if (kb < qt0) {
#pragma unroll
            for (int i2 = 0; i2 < 2; ++i2) {
                gl2lds16(kSrc[i2], &Ks[nxt][dstE[i2]]);
                gl2lds16(vSrc[i2], &Vs[nxt][dstE[i2]]);
                kSrc[i2] += 64 * HD;
                vSrc[i2] += 64;
            }
        }

        // QK^T for both tiles
        f32x4 accS0[4] = {}, accS1[4] = {};
#pragma unroll
        for (int ts = 0; ts < 4; ++ts) {
            accS0[ts] = __builtin_amdgcn_mfma_f32_16x16x32_bf16(ka[ts][0], qf[0][0], accS0[ts], 0, 0, 0);
            accS0[ts] = __builtin_amdgcn_mfma_f32_16x16x32_bf16(ka[ts][1], qf[0][1], accS0[ts], 0, 0, 0);
        }
        if (DO1) {
#pragma unroll
            for (int ts = 0; ts < 4; ++ts) {
                accS1[ts] = __builtin_amdgcn_mfma_f32_16x16x32_bf16(ka[ts][0], qf[1][0], accS1[ts], 0, 0, 0);
                accS1[ts] = __builtin_amdgcn_mfma_f32_16x16x32_bf16(ka[ts][1], qf[1][1], accS1[ts], 0, 0, 0);
            }
        }

        // tile 0: exp2 / mask / in-register pa build / PV
        {
            float pv[16];
#pragma unroll
            for (int ts = 0; ts < 4; ++ts)
#pragma unroll
                for (int r = 0; r < 4; ++r)
                    pv[4 * ts + r] = exp2f(accS0[ts][r]);
            if (M0) {
                // k-position of pv[4ts+r] is 32(ts>=2) + 8quad + 4(ts&1) + r
#pragma unroll
                for (int ts = 0; ts < 4; ++ts)
#pragma unroll
                    for (int r = 0; r < 4; ++r)
                        if ((((ts & 2) << 4) + ((ts & 1) << 2) + 8 * quad + r) > qi_l)
                            pv[4 * ts + r] = 0.f;
            }
            union { uint32_t u[4]; bf16x8 v; } A0, A1;
#pragma unroll
            for (int j = 0; j < 4; ++j) A0.u[j] = cvtpk(pv[2 * j],     pv[2 * j + 1]);
#pragma unroll
            for (int j = 0; j < 4; ++j) A1.u[j] = cvtpk(pv[8 + 2 * j], pv[9 + 2 * j]);
#pragma unroll
            for (int tn = 0; tn < 4; ++tn) {
                accO[0][tn] = __builtin_amdgcn_mfma_f32_16x16x32_bf16(A0.v, vb[tn][0], accO[0][tn], 0, 0, 0);
                accO[0][tn] = __builtin_amdgcn_mfma_f32_16x16x32_bf16(A1.v, vb[tn][1], accO[0][tn], 0, 0, 0);
            }
            accSum[0] = __builtin_amdgcn_mfma_f32_16x16x32_bf16(A0.v, ones, accSum[0], 0, 0, 0);
            accSum[0] = __builtin_amdgcn_mfma_f32_16x16x32_bf16(A1.v, ones, accSum[0], 0, 0, 0);
        }
        // tile 1
        if (DO1) {
            float pv[16];
#pragma unroll
            for (int ts = 0; ts < 4; ++ts)
#pragma unroll
                for (int r = 0; r < 4; ++r)
                    pv[4 * ts + r] = exp2f(accS1[ts][r]);
            if (M1) {
#pragma unroll
                for (int ts = 0; ts < 4; ++ts)
#pragma unroll
                    for (int r = 0; r < 4; ++r)
                        if ((((ts & 2) << 4) + ((ts & 1) << 2) + 8 * quad + r) > qi_l)
                            pv[4 * ts + r] = 0.f;
            }
            union { uint32_t u[4]; bf16x8 v; } A0, A1;
#pragma unroll
            for (int j = 0; j < 4; ++j) A0.u[j] = cvtpk(pv[2 * j],     pv[2 * j + 1]);
#pragma unroll
            for (int j = 0; j < 4; ++j) A1.u[j] = cvtpk(pv[8 + 2 * j], pv[9 + 2 * j]);
#pragma unroll
            for (int tn = 0; tn < 4; ++tn) {
                accO[1][tn] = __builtin_amdgcn_mfma_f32_16x16x32_bf16(A0.v, vb[tn][0], accO[1][tn], 0, 0, 0);
                accO[1][tn] = __builtin_amdgcn_mfma_f32_16x16x32_bf16(A1.v, vb[tn][1], accO[1][tn], 0, 0, 0);
            }
            accSum[1] = __builtin_amdgcn_mfma_f32_16x16x32_bf16(A0.v, ones, accSum[1], 0, 0, 0);
            accSum[1] = __builtin_amdgcn_mfma_f32_16x16x32_bf16(A1.v, ones, accSum[1], 0, 0, 0);
        }

        if (kb < qt0) __syncthreads();   // [cur] reads done; DMA for nxt drained
    };

    // ---- segmented k-loop: branch-free bodies, peeled diagonals ----
    for (int kb = 0; kb < qt1; ++kb) body(kb, true,  false, false);
    body(qt1, true,  false, true);                 // tile-1 diagonal
    for (int kb = qt1 + 1; kb < qt0; ++kb) body(kb, false, false, false);
    body(qt0, false, true,  false);                // tile-0 diagonal

    // ---- epilogue: denominator lane-aligned with accO rows ----
#pragma unroll
    for (int t = 0; t < 2; ++t) {
        const int q0t = t ? q01 : q00;
#pragma unroll
        for (int r = 0; r < 4; ++r) {
            float invr = 1.0f / accSum[t][r];
            const int row = q0t + 16 * w + 4 * quad + r;
#pragma unroll
            for (int tn = 0; tn < 4; ++tn)
                Out[(size_t)(b * SEQ + row) * EMB + h * HD + 16 * tn + l] =
                    accO[t][tn][r] * invr;
        }
    }
}

// =====================================================================
// Fallback (proven): fp32 vector GEMM (now writes bf16 Q, scaled).
// =====================================================================
__global__ __launch_bounds__(256) void qkv_gemm_vec(
    const float* __restrict__ X,  const float* __restrict__ Wq,
    const float* __restrict__ Wk, const float* __restrict__ Wv,
    uint16_t* __restrict__ Qbf, uint16_t* __restrict__ Kbf,
    uint16_t* __restrict__ Vtbf)
{
    const int tid = threadIdx.x;
    const int tx = tid & 15, ty = tid >> 4;
    const int bx = blockIdx.x;
    const int m0 = blockIdx.y * 64;

    const float* W; int ldw, n0;
    if (bx < 16)       { W = Wq; ldw = EMB; n0 = bx * 64; }
    else if (bx == 16) { W = Wk; ldw = HD;  n0 = 0; }
    else               { W = Wv; ldw = HD;  n0 = 0; }

    __shared__ float sA[64][17];
    __shared__ float sB[16][64];

    float acc[4][4] = {};
    const int arow = tid >> 2, acol = (tid & 3) * 4;
    const int brow = tid >> 4, bcol = (tid & 15) * 4;

    for (int k0 = 0; k0 < EMB; k0 += 16) {
        float4 fa = *(const float4*)&X[(size_t)(m0 + arow) * EMB + k0 + acol];
        float4 fb = *(const float4*)&W[(size_t)(k0 + brow) * ldw + n0 + bcol];
        sA[arow][acol + 0] = fa.x; sA[arow][acol + 1] = fa.y;
        sA[arow][acol + 2] = fa.z; sA[arow][acol + 3] = fa.w;
        sB[brow][bcol + 0] = fb.x; sB[brow][bcol + 1] = fb.y;
        sB[brow][bcol + 2] = fb.z; sB[brow][bcol + 3] = fb.w;
        __syncthreads();
#pragma unroll
        for (int kk = 0; kk < 16; ++kk) {
            float a0 = sA[4 * ty + 0][kk];
            float a1 = sA[4 * ty + 1][kk];
            float a2 = sA[4 * ty + 2][kk];
            float a3 = sA[4 * ty + 3][kk];
            float4 bq = *(const float4*)&sB[kk][4 * tx];
            acc[0][0] += a0 * bq.x; acc[0][1] += a0 * bq.y; acc[0][2] += a0 * bq.z; acc[0][3] += a0 * bq.w;
            acc[1][0] += a1 * bq.x; acc[1][1] += a1 * bq.y; acc[1][2] += a1 * bq.z; acc[1][3] += a1 * bq.w;
            acc[2][0] += a2 * bq.x; acc[2][1] += a2 * bq.y; acc[2][2] += a2 * bq.z; acc[2][3] += a2 * bq.w;
            acc[3][0] += a3 * bq.x; acc[3][1] += a3 * bq.y; acc[3][2] += a3 * bq.z; acc[3][3] += a3 * bq.w;
        }
        __syncthreads();
    }

    if (bx < 16) {
#pragma unroll
        for (int i = 0; i < 4; ++i) {
            ushort4 u; u.x = f2bf(acc[i][0] * CQ); u.y = f2bf(acc[i][1] * CQ);
            u.z = f2bf(acc[i][2] * CQ); u.w = f2bf(acc[i][3] * CQ);
            *(ushort4*)&Qbf[(size_t)(m0 + 4 * ty + i) * EMB + n0 + 4 * tx] = u;
        }
    } else if (bx == 16) {
#pragma unroll
        for (int i = 0; i < 4; ++i) {
            ushort4 u; u.x = f2bf(acc[i][0]); u.y = f2bf(acc[i][1]);
            u.z = f2bf(acc[i][2]); u.w = f2bf(acc[i][3]);
            *(ushort4*)&Kbf[(size_t)(m0 + 4 * ty + i) * HD + 4 * tx] = u;
        }
    } else {
#pragma unroll
        for (int j = 0; j < 4; ++j) {
            ushort4 u; u.x = f2bf(acc[0][j]); u.y = f2bf(acc[1][j]);
            u.z = f2bf(acc[2][j]); u.w = f2bf(acc[3][j]);
            *(ushort4*)&Vtbf[(size_t)(4 * tx + j) * NROW + m0 + 4 * ty] = u;
        }
    }
}

extern "C" void kernel_launch(void* const* d_in, const int* in_sizes, int n_in,
                              void* d_out, int out_size, void* d_ws, size_t ws_size,
                              hipStream_t stream) {
    const float* X  = (const float*)d_in[0];
    const float* Wq = (const float*)d_in[1];
    const float* Wk = (const float*)d_in[2];
    const float* Wv = (const float*)d_in[3];
    float* OutP = (float*)d_out;

    // ws layout (19.5 MiB):
    //   Xbf  [4096][1024] bf16   8 MiB  @ 0
    //   Qbf  [4096][1024] bf16   8 MiB  @ 8 MiB
    //   Wqt  [1024][1024] bf16   2 MiB  @ 16 MiB
    //   Wkt  [64][1024]   bf16 128 KiB  @ 18 MiB
    //   Wvt  [64][1024]   bf16 128 KiB  @ 18.25 MiB
    //   Kbf  [4096][64]   bf16 512 KiB  @ 18.5 MiB
    //   Vtbf [64][4096]   bf16 512 KiB  @ 19 MiB
    char* ws = (char*)d_ws;
    const size_t MB = 1024 * 1024;
    const size_t KB = 1024;
    uint16_t* Xbf  = (uint16_t*)(ws);
    uint16_t* Qbf  = (uint16_t*)(ws + 8 * MB);
    uint16_t* Wqt  = (uint16_t*)(ws + 16 * MB);
    uint16_t* Wkt  = (uint16_t*)(ws + 18 * MB);
    uint16_t* Wvt  = (uint16_t*)(ws + 18 * MB + 256 * KB);
    uint16_t* Kbf  = (uint16_t*)(ws + 18 * MB + 512 * KB);
    uint16_t* Vtbf = (uint16_t*)(ws + 19 * MB);

    if (ws_size >= 20 * MB) {
        prep<<<2336, 256, 0, stream>>>(X, Xbf, Wq, Wk, Wv, Wqt, Wkt, Wvt);
        qkv_gemm_mfma5<<<dim3(9, 64), 256, 0, stream>>>(Xbf, Wqt, Wkt, Wvt,
                                                        Qbf, Kbf, Vtbf);
        mqa_attn<<<dim3(16, NH, BSZ), 256, 0, stream>>>(Qbf, Kbf, Vtbf, OutP);
    } else {
        // fallback: Qbf @0 (8 MiB), Kbf @8 MiB, Vtbf @8.5 MiB (needs 9 MiB)
        uint16_t* QbfS  = (uint16_t*)ws;
        uint16_t* KbfS  = (uint16_t*)(ws + 8 * MB);
        uint16_t* VtbfS = (uint16_t*)(ws + 8 * MB + 512 * KB);
        qkv_gemm_vec<<<dim3(18, 64), 256, 0, stream>>>(X, Wq, Wk, Wv, QbfS, KbfS, VtbfS);
        mqa_attn<<<dim3(16, NH, BSZ), 256, 0, stream>>>(QbfS, KbfS, VtbfS, OutP);
    }
}

// Round 12
// 127.004 us; speedup vs baseline: 1.1963x; 1.0144x over previous
//
#include <hip/hip_runtime.h>
#include <stdint.h>

#define NH   16
#define EMB  1024
#define HD   64
#define BSZ  2
#define SEQ  2048
#define NROW (BSZ * SEQ)          // 4096

typedef __attribute__((ext_vector_type(8))) short bf16x8;   // 8 bf16 = 4 VGPRs
typedef __attribute__((ext_vector_type(4))) float f32x4;    // MFMA C/D

#define CQ 0.18033688011112042f   // 0.125 * log2(e), folded into Wq

__device__ __forceinline__ uint16_t f2bf(float f) {
    union { float f; uint32_t i; } v; v.f = f;
    uint32_t r = v.i + 0x7FFFu + ((v.i >> 16) & 1u);  // RNE
    return (uint16_t)(r >> 16);
}
__device__ __forceinline__ uint32_t pack2(float a, float b) {
    return (uint32_t)f2bf(a) | ((uint32_t)f2bf(b) << 16);
}
// single-instruction packed f32->bf16 (lo=a, hi=b), RNE
__device__ __forceinline__ uint32_t cvtpk(float a, float b) {
    uint32_t r;
    asm("v_cvt_pk_bf16_f32 %0, %1, %2" : "=v"(r) : "v"(a), "v"(b));
    return r;
}

// async global->LDS, 16 B per lane, wave-uniform LDS base
__device__ __forceinline__ void gl2lds16(const uint16_t* g, uint16_t* l) {
    __builtin_amdgcn_global_load_lds(
        static_cast<const uint32_t*>(static_cast<const void*>(g)),
        static_cast<uint32_t*>(static_cast<void*>(l)), 16, 0, 0);
}

// =====================================================================
// Prep (fused): blocks 0..2047 convert X fp32->bf16;
// blocks 2048..2335 transpose W fp32 [k][n] -> bf16 Wt[n][k].
// Wq pre-scaled by CQ so Q leaves the GEMM softmax-ready.
// =====================================================================
__global__ __launch_bounds__(256) void prep(
    const float* __restrict__ X, uint16_t* __restrict__ Xbf,
    const float* __restrict__ Wq, const float* __restrict__ Wk,
    const float* __restrict__ Wv, uint16_t* __restrict__ Wqt,
    uint16_t* __restrict__ Wkt, uint16_t* __restrict__ Wvt)
{
    __shared__ uint16_t T[64][72];
    const int tid = threadIdx.x;
    if (blockIdx.x < 2048) {
        size_t idx = ((size_t)blockIdx.x * 256 + tid) * 8;
        float4 a = *(const float4*)&X[idx];
        float4 b = *(const float4*)&X[idx + 4];
        *(uint4*)&Xbf[idx] = make_uint4(pack2(a.x, a.y), pack2(a.z, a.w),
                                        pack2(b.x, b.y), pack2(b.z, b.w));
        return;
    }
    const int id = blockIdx.x - 2048;
    const float* W; uint16_t* Wt; int k0, n0, ldw;
    if (id < 256)      { W = Wq; Wt = Wqt; k0 = (id >> 4) * 64; n0 = (id & 15) * 64; ldw = EMB; }
    else if (id < 272) { W = Wk; Wt = Wkt; k0 = (id - 256) * 64; n0 = 0; ldw = HD; }
    else               { W = Wv; Wt = Wvt; k0 = (id - 272) * 64; n0 = 0; ldw = HD; }
    const float scl = (id < 256) ? CQ : 1.0f;

    const int r = tid >> 2, c4 = (tid & 3) * 16;
#pragma unroll
    for (int i = 0; i < 4; ++i) {
        float4 wv = *(const float4*)&W[(size_t)(k0 + r) * ldw + n0 + c4 + 4 * i];
        T[r][c4 + 4 * i + 0] = f2bf(wv.x * scl); T[r][c4 + 4 * i + 1] = f2bf(wv.y * scl);
        T[r][c4 + 4 * i + 2] = f2bf(wv.z * scl); T[r][c4 + 4 * i + 3] = f2bf(wv.w * scl);
    }
    __syncthreads();
    const int n = tid >> 2, kk = (tid & 3) * 16;
    uint32_t o[8];
#pragma unroll
    for (int i = 0; i < 8; ++i)
        o[i] = (uint32_t)T[kk + 2 * i][n] | ((uint32_t)T[kk + 2 * i + 1][n] << 16);
    uint16_t* dst = &Wt[(size_t)(n0 + n) * EMB + k0 + kk];
    *(uint4*)dst       = make_uint4(o[0], o[1], o[2], o[3]);
    *(uint4*)(dst + 8) = make_uint4(o[4], o[5], o[6], o[7]);
}

// =====================================================================
// Kernel 1: MFMA projection GEMM v5 + XCD-chunked block swizzle
// (R10/R11-proven).  Q written as bf16 (pre-scaled via Wqt).
// =====================================================================
__global__ __launch_bounds__(256) void qkv_gemm_mfma5(
    const uint16_t* __restrict__ Xbf, const uint16_t* __restrict__ Wqt,
    const uint16_t* __restrict__ Wkt, const uint16_t* __restrict__ Wvt,
    uint16_t* __restrict__ Qbf, uint16_t* __restrict__ Kbf,
    uint16_t* __restrict__ Vtbf)
{
    const int tid  = threadIdx.x;
    const int w    = tid >> 6, lane = tid & 63;
    const int l    = lane & 15, quad = lane >> 4;
    const int wm   = w & 1, wn = w >> 1;      // wave: 32m x 64n quadrant

    // ---- XCD-chunked swizzle (bijective on 0..575) ----
    const int lin  = blockIdx.x + 9 * blockIdx.y;
    const int lin2 = (lin & 7) * 72 + (lin >> 3);
    const int nt   = lin2 % 9;
    const int m0   = (lin2 / 9) * 64;

    __shared__ uint16_t As[2][64 * 64];    // 8 KB per buffer
    __shared__ uint16_t Bs[2][128 * 64];   // 16 KB per buffer

    const uint16_t* gA[2]; uint32_t ldsA[2];
    const uint16_t* gB[4]; uint32_t ldsB[4];
#pragma unroll
    for (int i = 0; i < 2; ++i) {
        int G = (w * 2 + i) * 64 + lane;
        int r = G >> 3, cg = (G & 7) ^ (r & 7);
        gA[i] = &Xbf[(size_t)(m0 + r) * EMB + cg * 8];
        ldsA[i] = (w * 2 + i) * 512;              // elems, wave-uniform
    }
#pragma unroll
    for (int i = 0; i < 4; ++i) {
        int G = (w * 4 + i) * 64 + lane;
        int r = G >> 3, cg = (G & 7) ^ (r & 7);
        const uint16_t* bs;
        if (nt < 8)      bs = &Wqt[(size_t)(nt * 128 + r) * EMB + cg * 8];
        else if (r < 64) bs = &Wkt[(size_t)r * EMB + cg * 8];
        else             bs = &Wvt[(size_t)(r - 64) * EMB + cg * 8];
        gB[i] = bs;
        ldsB[i] = (w * 4 + i) * 512;
    }

    uint32_t offA[2][2], offB[4][2];
#pragma unroll
    for (int i = 0; i < 2; ++i)
#pragma unroll
        for (int kh = 0; kh < 2; ++kh) {
            int row = 32 * wm + 16 * i + l;
            offA[i][kh] = row * 64 + (((kh * 4 + quad) ^ (row & 7)) * 8);
        }
#pragma unroll
    for (int j = 0; j < 4; ++j)
#pragma unroll
        for (int kh = 0; kh < 2; ++kh) {
            int row = 64 * wn + 16 * j + l;
            offB[j][kh] = row * 64 + (((kh * 4 + quad) ^ (row & 7)) * 8);
        }

    f32x4 acc[2][4] = {};

#pragma unroll
    for (int i = 0; i < 2; ++i) { gl2lds16(gA[i], &As[0][ldsA[i]]); gA[i] += 64; }
#pragma unroll
    for (int i = 0; i < 4; ++i) { gl2lds16(gB[i], &Bs[0][ldsB[i]]); gB[i] += 64; }
    __syncthreads();

    for (int ks = 0; ks < 16; ++ks) {
        const int cur = ks & 1, nxt = cur ^ 1;
        if (ks < 15) {
#pragma unroll
            for (int i = 0; i < 2; ++i) { gl2lds16(gA[i], &As[nxt][ldsA[i]]); gA[i] += 64; }
#pragma unroll
            for (int i = 0; i < 4; ++i) { gl2lds16(gB[i], &Bs[nxt][ldsB[i]]); gB[i] += 64; }
        }
#pragma unroll
        for (int kh = 0; kh < 2; ++kh) {
            bf16x8 af[2], bfr[4];
#pragma unroll
            for (int i = 0; i < 2; ++i) af[i] = *(const bf16x8*)&As[cur][offA[i][kh]];
#pragma unroll
            for (int j = 0; j < 4; ++j) bfr[j] = *(const bf16x8*)&Bs[cur][offB[j][kh]];
#pragma unroll
            for (int i = 0; i < 2; ++i)
#pragma unroll
                for (int j = 0; j < 4; ++j)
                    acc[i][j] = __builtin_amdgcn_mfma_f32_16x16x32_bf16(
                        af[i], bfr[j], acc[i][j], 0, 0, 0);
        }
        __syncthreads();
    }

    if (nt < 8) {             // Q -> bf16 workspace (pre-scaled via Wqt)
#pragma unroll
        for (int i = 0; i < 2; ++i)
#pragma unroll
            for (int j = 0; j < 4; ++j)
#pragma unroll
                for (int r = 0; r < 4; ++r)
                    Qbf[(size_t)(m0 + 32 * wm + 16 * i + 4 * quad + r) * EMB
                        + nt * 128 + 64 * wn + 16 * j + l] = f2bf(acc[i][j][r]);
    } else if (wn == 0) {     // K -> bf16 [t][d]
#pragma unroll
        for (int i = 0; i < 2; ++i)
#pragma unroll
            for (int j = 0; j < 4; ++j)
#pragma unroll
                for (int r = 0; r < 4; ++r)
                    Kbf[(size_t)(m0 + 32 * wm + 16 * i + 4 * quad + r) * HD
                        + 16 * j + l] = f2bf(acc[i][j][r]);
    } else {                  // V -> bf16 transposed [d][t]
#pragma unroll
        for (int i = 0; i < 2; ++i)
#pragma unroll
            for (int j = 0; j < 4; ++j)
#pragma unroll
                for (int r = 0; r < 4; ++r)
                    Vtbf[(size_t)(16 * j + l) * NROW
                         + m0 + 32 * wm + 16 * i + 4 * quad + r] = f2bf(acc[i][j][r]);
    }
}

// =====================================================================
// Kernel 2: causal MQA flash attention, COMPLEMENTARY-PAIR blocks.
// R22: 2-way KEY SPLIT across waves -- wave (wq=w&1, wk=w>>1) owns
// q-rows 32wq..+31 x keys 32wk..+31 of BOTH tiles.  Per-wave in-loop
// LDS reads HALVE (4 K + 4 V b128, was 8+8).  MFMA/exp2/cvtpk per
// wave unchanged (work redistributed).  Cross-wave combine through a
// DEDICATED LDS buffer (XB/SB -- never a DMA target; R9's failed
// attempt aliased the exchange onto global_load_lds destinations),
// two-phase with wave-uniform barriers.  LDS 68 KB -> 2 blocks/CU.
// Verified mappings: pi(32wk+16ts+4quad+r) = 32wk+8quad+4ts+r, so a
// lane's 8 pv values per (tile,qs) ARE one K=32 PV A-fragment.
// Grid (16, NH, BSZ) = 512 blocks.
// =====================================================================
__global__ __launch_bounds__(256) void mqa_attn(
    const uint16_t* __restrict__ Qbf, const uint16_t* __restrict__ Kbf,
    const uint16_t* __restrict__ Vtbf, float* __restrict__ Out)
{
    const int tid  = threadIdx.x;
    const int w    = tid >> 6;
    const int lane = tid & 63;
    const int l    = lane & 15;
    const int quad = lane >> 4;
    const int wq   = w & 1;               // q-half owned by this wave
    const int wk   = w >> 1;              // key-half owned by this wave
    const int i  = blockIdx.x;            // 0..15 (i=0 longest)
    const int h  = blockIdx.y, b = blockIdx.z;
    const int qt0 = 31 - i, qt1 = i;      // big, small q-tile
    const int q00 = qt0 * 64, q01 = qt1 * 64;

    __shared__ __align__(16) uint16_t Ks[2][4096];  // K dbuf (pi rows, swz) 16 KB
    __shared__ __align__(16) uint16_t Vs[2][4096];  // V^T dbuf (swz)        16 KB
    __shared__ __align__(16) uint16_t Ps[2][4096];  // Q tiles (swz)         16 KB
    __shared__ __align__(16) float    XB[16][64][4];// O-partial xchg        16 KB
    __shared__ __align__(16) float    SB[4][64][4]; // sum-partial xchg       4 KB

    // ---- DMA staging sources (R11-proven) ----
    const uint16_t* kSrc[2]; const uint16_t* vSrc[2]; uint32_t dstE[2];
#pragma unroll
    for (int i2 = 0; i2 < 2; ++i2) {
        int G = (w * 2 + i2) * 64 + lane;
        int r = G >> 3, g = G & 7;
        int pr = (r & 32) + ((r >> 2) & 3) * 8 + ((r & 16) >> 2) + (r & 3);
        int cg = g ^ (r & 7);
        kSrc[i2] = &Kbf[(size_t)(b * SEQ + pr) * HD + cg * 8];
        vSrc[i2] = &Vtbf[(size_t)r * NROW + b * SEQ + cg * 8];
        dstE[i2] = (uint32_t)(w * 2 + i2) * 512;   // elems
    }

    // ---- stage K/V tile 0 + both Q tiles via DMA ----
#pragma unroll
    for (int i2 = 0; i2 < 2; ++i2) {
        gl2lds16(kSrc[i2], &Ks[0][dstE[i2]]);
        gl2lds16(vSrc[i2], &Vs[0][dstE[i2]]);
        kSrc[i2] += 64 * HD;   // next k-tile = +64 rows
        vSrc[i2] += 64;        // next k-tile = +64 cols
    }
#pragma unroll
    for (int t = 0; t < 2; ++t) {
        const int q0t = t ? q01 : q00;
#pragma unroll
        for (int i2 = 0; i2 < 2; ++i2) {
            int G = (w * 2 + i2) * 64 + lane;
            int r = G >> 3, g = G & 7;
            int cg = g ^ (r & 7);
            gl2lds16(&Qbf[(size_t)(b * SEQ + q0t + r) * EMB + h * HD + cg * 8],
                     &Ps[t][dstE[i2]]);
        }
    }
    __syncthreads();   // drains all DMA (vmcnt)

    // ---- Q B-fragments: [tile][qs][kh], q rows 32wq+16qs+l ----
    bf16x8 qf[2][2][2];
#pragma unroll
    for (int t = 0; t < 2; ++t)
#pragma unroll
        for (int qs = 0; qs < 2; ++qs) {
            const int row = 32 * wq + 16 * qs + l;
            qf[t][qs][0] = *(const bf16x8*)&Ps[t][row * 64 + (((0 + quad) ^ (row & 7)) * 8)];
            qf[t][qs][1] = *(const bf16x8*)&Ps[t][row * 64 + (((4 + quad) ^ (row & 7)) * 8)];
        }

    // ---- loop-invariant LDS read offsets (this wave's halves) ----
    uint32_t offK[2][2], offV[4];
#pragma unroll
    for (int ts = 0; ts < 2; ++ts)
#pragma unroll
        for (int kh = 0; kh < 2; ++kh) {
            int row = 32 * wk + 16 * ts + l;
            offK[ts][kh] = row * 64 + (((kh * 4 + quad) ^ (row & 7)) * 8);
        }
#pragma unroll
    for (int tn = 0; tn < 4; ++tn) {
        int row = 16 * tn + l;
        offV[tn] = row * 64 + (((4 * wk + quad) ^ (row & 7)) * 8);
    }

    bf16x8 ones;
#pragma unroll
    for (int j = 0; j < 8; ++j) ones[j] = (short)0x3F80;   // bf16 1.0

    f32x4 accO[2][2][4] = {};   // [tile][qs][tn], partial over wave's keys
    f32x4 accSum[2][2] = {};    // [tile][qs]

    // ---- one k-tile step; DO1/M0/M1 compile-time at each call site ----
    auto body = [&](int kb, bool DO1, bool M0, bool M1) __attribute__((always_inline)) {
        const int cur = kb & 1, nxt = cur ^ 1;

        // K / V fragments from LDS (this wave's key-half only)
        bf16x8 ka[2][2], vb[4];
#pragma unroll
        for (int ts = 0; ts < 2; ++ts) {
            ka[ts][0] = *(const bf16x8*)&Ks[cur][offK[ts][0]];
            ka[ts][1] = *(const bf16x8*)&Ks[cur][offK[ts][1]];
        }
#pragma unroll
        for (int tn = 0; tn < 4; ++tn)
            vb[tn] = *(const bf16x8*)&Vs[cur][offV[tn]];

        // DMA-stage tile kb+1 into idle buffers
        if (kb < qt0) {
#pragma unroll
            for (int i2 = 0; i2 < 2; ++i2) {
                gl2lds16(kSrc[i2], &Ks[nxt][dstE[i2]]);
                gl2lds16(vSrc[i2], &Vs[nxt][dstE[i2]]);
                kSrc[i2] += 64 * HD;
                vSrc[i2] += 64;
            }
        }

        // ---- per-tile compute (tile 0 always; tile 1 if DO1) ----
#pragma unroll
        for (int t = 0; t < 2; ++t) {
            if (t == 1 && !DO1) break;
            const bool M = t ? M1 : M0;
            f32x4 accS[2][2] = {};   // [qs][ts]
#pragma unroll
            for (int qs = 0; qs < 2; ++qs)
#pragma unroll
                for (int ts = 0; ts < 2; ++ts) {
                    accS[qs][ts] = __builtin_amdgcn_mfma_f32_16x16x32_bf16(
                        ka[ts][0], qf[t][qs][0], accS[qs][ts], 0, 0, 0);
                    accS[qs][ts] = __builtin_amdgcn_mfma_f32_16x16x32_bf16(
                        ka[ts][1], qf[t][qs][1], accS[qs][ts], 0, 0, 0);
                }
#pragma unroll
            for (int qs = 0; qs < 2; ++qs) {
                float pvq[8];
#pragma unroll
                for (int ts = 0; ts < 2; ++ts)
#pragma unroll
                    for (int r = 0; r < 4; ++r)
                        pvq[4 * ts + r] = exp2f(accS[qs][ts][r]);
                if (M) {
                    // key = 32wk + 8quad + 4ts + r ; q = 32wq + 16qs + l
#pragma unroll
                    for (int ts = 0; ts < 2; ++ts)
#pragma unroll
                        for (int r = 0; r < 4; ++r)
                            if ((32 * wk + 8 * quad + 4 * ts + r) >
                                (32 * wq + 16 * qs + l))
                                pvq[4 * ts + r] = 0.f;
                }
                union { uint32_t u[4]; bf16x8 v; } A;
#pragma unroll
                for (int j = 0; j < 4; ++j)
                    A.u[j] = cvtpk(pvq[2 * j], pvq[2 * j + 1]);
#pragma unroll
                for (int tn = 0; tn < 4; ++tn)
                    accO[t][qs][tn] = __builtin_amdgcn_mfma_f32_16x16x32_bf16(
                        A.v, vb[tn], accO[t][qs][tn], 0, 0, 0);
                accSum[t][qs] = __builtin_amdgcn_mfma_f32_16x16x32_bf16(
                    A.v, ones, accSum[t][qs], 0, 0, 0);
            }
        }

        if (kb < qt0) __syncthreads();   // [cur] reads done; DMA drained
    };

    // ---- segmented k-loop: branch-free bodies, peeled diagonals ----
    for (int kb = 0; kb < qt1; ++kb) body(kb, true,  false, false);
    body(qt1, true,  false, true);                 // tile-1 diagonal
    for (int kb = qt1 + 1; kb < qt0; ++kb) body(kb, false, false, false);
    body(qt0, false, true,  false);                // tile-0 diagonal

    // ============ two-phase cross-wave reduction (dedicated LDS) ========
    __syncthreads();                      // all loop work done

    // ---- phase A: tile 0.  wk=1 waves publish; wk=0 finalize. ----
    if (wk == 1) {
#pragma unroll
        for (int qs = 0; qs < 2; ++qs) {
#pragma unroll
            for (int tn = 0; tn < 4; ++tn)
                *(f32x4*)&XB[(wq * 2 + qs) * 4 + tn][lane][0] = accO[0][qs][tn];
            *(f32x4*)&SB[wq * 2 + qs][lane][0] = accSum[0][qs];
        }
    }
    __syncthreads();
    if (wk == 0) {
#pragma unroll
        for (int qs = 0; qs < 2; ++qs) {
            f32x4 stot = accSum[0][qs];
            stot += *(const f32x4*)&SB[wq * 2 + qs][lane][0];
#pragma unroll
            for (int r = 0; r < 4; ++r) {
                float inv = 1.0f / stot[r];
                const int row = q00 + 32 * wq + 16 * qs + 4 * quad + r;
#pragma unroll
                for (int tn = 0; tn < 4; ++tn) {
                    float o = accO[0][qs][tn][r] +
                              XB[(wq * 2 + qs) * 4 + tn][lane][r];
                    Out[(size_t)(b * SEQ + row) * EMB + h * HD + 16 * tn + l] =
                        o * inv;
                }
            }
        }
    }
    __syncthreads();

    // ---- phase B: tile 1.  wk=0 waves publish; wk=1 finalize. ----
    if (wk == 0) {
#pragma unroll
        for (int qs = 0; qs < 2; ++qs) {
#pragma unroll
            for (int tn = 0; tn < 4; ++tn)
                *(f32x4*)&XB[(wq * 2 + qs) * 4 + tn][lane][0] = accO[1][qs][tn];
            *(f32x4*)&SB[wq * 2 + qs][lane][0] = accSum[1][qs];
        }
    }
    __syncthreads();
    if (wk == 1) {
#pragma unroll
        for (int qs = 0; qs < 2; ++qs) {
            f32x4 stot = accSum[1][qs];
            stot += *(const f32x4*)&SB[wq * 2 + qs][lane][0];
#pragma unroll
            for (int r = 0; r < 4; ++r) {
                float inv = 1.0f / stot[r];
                const int row = q01 + 32 * wq + 16 * qs + 4 * quad + r;
#pragma unroll
                for (int tn = 0; tn < 4; ++tn) {
                    float o = accO[1][qs][tn][r] +
                              XB[(wq * 2 + qs) * 4 + tn][lane][r];
                    Out[(size_t)(b * SEQ + row) * EMB + h * HD + 16 * tn + l] =
                        o * inv;
                }
            }
        }
    }
}

// =====================================================================
// Fallback (proven): fp32 vector GEMM (writes bf16 Q, scaled).
// =====================================================================
__global__ __launch_bounds__(256) void qkv_gemm_vec(
    const float* __restrict__ X,  const float* __restrict__ Wq,
    const float* __restrict__ Wk, const float* __restrict__ Wv,
    uint16_t* __restrict__ Qbf, uint16_t* __restrict__ Kbf,
    uint16_t* __restrict__ Vtbf)
{
    const int tid = threadIdx.x;
    const int tx = tid & 15, ty = tid >> 4;
    const int bx = blockIdx.x;
    const int m0 = blockIdx.y * 64;

    const float* W; int ldw, n0;
    if (bx < 16)       { W = Wq; ldw = EMB; n0 = bx * 64; }
    else if (bx == 16) { W = Wk; ldw = HD;  n0 = 0; }
    else               { W = Wv; ldw = HD;  n0 = 0; }

    __shared__ float sA[64][17];
    __shared__ float sB[16][64];

    float acc[4][4] = {};
    const int arow = tid >> 2, acol = (tid & 3) * 4;
    const int brow = tid >> 4, bcol = (tid & 15) * 4;

    for (int k0 = 0; k0 < EMB; k0 += 16) {
        float4 fa = *(const float4*)&X[(size_t)(m0 + arow) * EMB + k0 + acol];
        float4 fb = *(const float4*)&W[(size_t)(k0 + brow) * ldw + n0 + bcol];
        sA[arow][acol + 0] = fa.x; sA[arow][acol + 1] = fa.y;
        sA[arow][acol + 2] = fa.z; sA[arow][acol + 3] = fa.w;
        sB[brow][bcol + 0] = fb.x; sB[brow][bcol + 1] = fb.y;
        sB[brow][bcol + 2] = fb.z; sB[brow][bcol + 3] = fb.w;
        __syncthreads();
#pragma unroll
        for (int kk = 0; kk < 16; ++kk) {
            float a0 = sA[4 * ty + 0][kk];
            float a1 = sA[4 * ty + 1][kk];
            float a2 = sA[4 * ty + 2][kk];
            float a3 = sA[4 * ty + 3][kk];
            float4 bq = *(const float4*)&sB[kk][4 * tx];
            acc[0][0] += a0 * bq.x; acc[0][1] += a0 * bq.y; acc[0][2] += a0 * bq.z; acc[0][3] += a0 * bq.w;
            acc[1][0] += a1 * bq.x; acc[1][1] += a1 * bq.y; acc[1][2] += a1 * bq.z; acc[1][3] += a1 * bq.w;
            acc[2][0] += a2 * bq.x; acc[2][1] += a2 * bq.y; acc[2][2] += a2 * bq.z; acc[2][3] += a2 * bq.w;
            acc[3][0] += a3 * bq.x; acc[3][1] += a3 * bq.y; acc[3][2] += a3 * bq.z; acc[3][3] += a3 * bq.w;
        }
        __syncthreads();
    }

    if (bx < 16) {
#pragma unroll
        for (int i = 0; i < 4; ++i) {
            ushort4 u; u.x = f2bf(acc[i][0] * CQ); u.y = f2bf(acc[i][1] * CQ);
            u.z = f2bf(acc[i][2] * CQ); u.w = f2bf(acc[i][3] * CQ);
            *(ushort4*)&Qbf[(size_t)(m0 + 4 * ty + i) * EMB + n0 + 4 * tx] = u;
        }
    } else if (bx == 16) {
#pragma unroll
        for (int i = 0; i < 4; ++i) {
            ushort4 u; u.x = f2bf(acc[i][0]); u.y = f2bf(acc[i][1]);
            u.z = f2bf(acc[i][2]); u.w = f2bf(acc[i][3]);
            *(ushort4*)&Kbf[(size_t)(m0 + 4 * ty + i) * HD + 4 * tx] = u;
        }
    } else {
#pragma unroll
        for (int j = 0; j < 4; ++j) {
            ushort4 u; u.x = f2bf(acc[0][j]); u.y = f2bf(acc[1][j]);
            u.z = f2bf(acc[2][j]); u.w = f2bf(acc[3][j]);
            *(ushort4*)&Vtbf[(size_t)(4 * tx + j) * NROW + m0 + 4 * ty] = u;
        }
    }
}

extern "C" void kernel_launch(void* const* d_in, const int* in_sizes, int n_in,
                              void* d_out, int out_size, void* d_ws, size_t ws_size,
                              hipStream_t stream) {
    const float* X  = (const float*)d_in[0];
    const float* Wq = (const float*)d_in[1];
    const float* Wk = (const float*)d_in[2];
    const float* Wv = (const float*)d_in[3];
    float* OutP = (float*)d_out;

    // ws layout (19.5 MiB):
    //   Xbf  [4096][1024] bf16   8 MiB  @ 0
    //   Qbf  [4096][1024] bf16   8 MiB  @ 8 MiB
    //   Wqt  [1024][1024] bf16   2 MiB  @ 16 MiB
    //   Wkt  [64][1024]   bf16 128 KiB  @ 18 MiB
    //   Wvt  [64][1024]   bf16 128 KiB  @ 18.25 MiB
    //   Kbf  [4096][64]   bf16 512 KiB  @ 18.5 MiB
    //   Vtbf [64][4096]   bf16 512 KiB  @ 19 MiB
    char* ws = (char*)d_ws;
    const size_t MB = 1024 * 1024;
    const size_t KB = 1024;
    uint16_t* Xbf  = (uint16_t*)(ws);
    uint16_t* Qbf  = (uint16_t*)(ws + 8 * MB);
    uint16_t* Wqt  = (uint16_t*)(ws + 16 * MB);
    uint16_t* Wkt  = (uint16_t*)(ws + 18 * MB);
    uint16_t* Wvt  = (uint16_t*)(ws + 18 * MB + 256 * KB);
    uint16_t* Kbf  = (uint16_t*)(ws + 18 * MB + 512 * KB);
    uint16_t* Vtbf = (uint16_t*)(ws + 19 * MB);

    if (ws_size >= 20 * MB) {
        prep<<<2336, 256, 0, stream>>>(X, Xbf, Wq, Wk, Wv, Wqt, Wkt, Wvt);
        qkv_gemm_mfma5<<<dim3(9, 64), 256, 0, stream>>>(Xbf, Wqt, Wkt, Wvt,
                                                        Qbf, Kbf, Vtbf);
        mqa_attn<<<dim3(16, NH, BSZ), 256, 0, stream>>>(Qbf, Kbf, Vtbf, OutP);
    } else {
        // fallback: Qbf @0 (8 MiB), Kbf @8 MiB, Vtbf @8.5 MiB (needs 9 MiB)
        uint16_t* QbfS  = (uint16_t*)ws;
        uint16_t* KbfS  = (uint16_t*)(ws + 8 * MB);
        uint16_t* VtbfS = (uint16_t*)(ws + 8 * MB + 512 * KB);
        qkv_gemm_vec<<<dim3(18, 64), 256, 0, stream>>>(X, Wq, Wk, Wv, QbfS, KbfS, VtbfS);
        mqa_attn<<<dim3(16, NH, BSZ), 256, 0, stream>>>(QbfS, KbfS, VtbfS, OutP);
    }
}